// Round 7
// baseline (556.032 us; speedup 1.0000x reference)
//
#include <hip/hip_runtime.h>
#include <math.h>

// Bamba-9B mixer, b=1 s=2048. Round 14: fix round-13's VGPR spill.
//  - Round-13 counters: WRITE_SIZE 249MB (vs 64MB output), FETCH +8MB,
//    VGPR_Count 128 -> the phase-ahead register prefetch (acc 128 + frags
//    ~96 + addr ~16 = ~240 VGPRs) got allocated at 128 VGPRs (compiler
//    targeted 4 waves/SIMD without a launch-bounds hint) and spilled to
//    scratch every phase: ~185MB/dispatch of HBM spill traffic, MfmaUtil 17%.
//  - Fix: __launch_bounds__(512, 2) — 2 waves/SIMD = 1 block/CU, which the
//    128KiB LDS already imposes; VGPR cap 256/wave, schedule fits spill-free.
// Everything else unchanged from round 13.
static constexpr int kS     = 2048;
static constexpr int kHID   = 2048;
static constexpr int kI     = 4096;
static constexpr int kH     = 64;
static constexpr int kP     = 64;
static constexpr int kN     = 128;
static constexpr int kConv  = 4352;   // I + 2*G*N
static constexpr int kProj  = 8512;   // I + CONV + H
static constexpr int kChunk = 256;
static constexpr int kNC    = 8;
static constexpr float kEps = 1e-5f;

typedef __attribute__((ext_vector_type(8))) short short8;            // bf16 frag
typedef __attribute__((ext_vector_type(8))) unsigned short ushort8v;
typedef __attribute__((ext_vector_type(4))) float floatx4;

__device__ __forceinline__ float siluf(float x) {
    return x / (1.f + __expf(-x));
}
__device__ __forceinline__ unsigned short f2bf(float f) {   // RNE, finite
    unsigned int u = __float_as_uint(f);
    return (unsigned short)((u + 0x7FFFu + ((u >> 16) & 1u)) >> 16);
}
__device__ __forceinline__ float bf2f(unsigned short u) {
    return __uint_as_float((unsigned int)u << 16);
}
__device__ __forceinline__ void gll16(const void* g, void* l) {
    __builtin_amdgcn_global_load_lds(
        (const __attribute__((address_space(1))) void*)g,
        (__attribute__((address_space(3))) void*)l, 16, 0, 0);
}

// ---------- fp32 -> bf16 cast, 8 elems/thread ----------
__global__ __launch_bounds__(256)
void cast_bf16_k(const float* __restrict__ in, unsigned short* __restrict__ out)
{
    size_t i = ((size_t)blockIdx.x * 256 + threadIdx.x) * 8;
    float4 a = *(const float4*)&in[i];
    float4 b = *(const float4*)&in[i + 4];
    ushort4 u0 = {f2bf(a.x), f2bf(a.y), f2bf(a.z), f2bf(a.w)};
    ushort4 u1 = {f2bf(b.x), f2bf(b.y), f2bf(b.z), f2bf(b.w)};
    *(ushort4*)&out[i] = u0;
    *(ushort4*)&out[i + 4] = u1;
}

// ---------- 256x256-tile pipelined 8-phase bf16 NT GEMM, split-K ----------
// M%256==0, N%256==0, K%256==0. grid = nsplit*(M/256)*(N/256).
// Buffers: [2 kh][256 rows][32 shorts] per array. Per phase: {barrier;
// prio1; issue NEXT phase's ds_reads; issue this phase's gll16 stage;
// 16 MFMA; prio0; [vmcnt(8) at end of ph1/ph3]}. Reads precede the stage in
// program order (no compiler hazard wait); vmcnt->barrier->reads gives the
// cross-wave staging guarantee. In-flight depth: 8 loads (4 stages).
#define MF16(acc_, a_, b_) \
    acc_ = __builtin_amdgcn_mfma_f32_16x16x32_bf16(a_, b_, acc_, 0, 0, 0)

#define PH1(LB_, ST_)                                                          \
    __builtin_amdgcn_s_barrier();                                              \
    __builtin_amdgcn_s_setprio(1);                                             \
    bLo2 = *(const short8*)&(LB_)[boff2 + (2 << 9)];                           \
    bLo3 = *(const short8*)&(LB_)[boff2 + (3 << 9)];                           \
    ST_;                                                                       \
    _Pragma("unroll")                                                          \
    for (int m = 0; m < 8; ++m) {                                              \
        MF16(acc[m][0], aLo[m], bLo0);                                         \
        MF16(acc[m][1], aLo[m], bLo1);                                         \
    }                                                                          \
    __builtin_amdgcn_s_setprio(0);                                             \
    asm volatile("s_waitcnt vmcnt(8)" ::: "memory");

#define PH2(LA_, LB_, ST_)                                                     \
    __builtin_amdgcn_s_barrier();                                              \
    __builtin_amdgcn_s_setprio(1);                                             \
    _Pragma("unroll")                                                          \
    for (int m = 0; m < 8; ++m)                                                \
        aHi[m] = *(const short8*)&(LA_)[8192 + aoff2 + (m << 9)];              \
    bHi0 = *(const short8*)&(LB_)[8192 + boff2];                               \
    bHi1 = *(const short8*)&(LB_)[8192 + boff2 + (1 << 9)];                    \
    ST_;                                                                       \
    _Pragma("unroll")                                                          \
    for (int m = 0; m < 8; ++m) {                                              \
        MF16(acc[m][2], aLo[m], bLo2);                                         \
        MF16(acc[m][3], aLo[m], bLo3);                                         \
    }                                                                          \
    __builtin_amdgcn_s_setprio(0);

#define PH3(LB_, ST_, VM_)                                                     \
    __builtin_amdgcn_s_barrier();                                              \
    __builtin_amdgcn_s_setprio(1);                                             \
    bHi2 = *(const short8*)&(LB_)[8192 + boff2 + (2 << 9)];                    \
    bHi3 = *(const short8*)&(LB_)[8192 + boff2 + (3 << 9)];                    \
    ST_;                                                                       \
    _Pragma("unroll")                                                          \
    for (int m = 0; m < 8; ++m) {                                              \
        MF16(acc[m][0], aHi[m], bHi0);                                         \
        MF16(acc[m][1], aHi[m], bHi1);                                         \
    }                                                                          \
    __builtin_amdgcn_s_setprio(0);                                             \
    VM_;

#define PH4(LAn_, LBn_, ST_, DOR_)                                             \
    __builtin_amdgcn_s_barrier();                                              \
    __builtin_amdgcn_s_setprio(1);                                             \
    if (DOR_) {                                                                \
        _Pragma("unroll")                                                      \
        for (int m = 0; m < 8; ++m)                                            \
            aLo[m] = *(const short8*)&(LAn_)[aoff2 + (m << 9)];                \
        bLo0 = *(const short8*)&(LBn_)[boff2];                                 \
        bLo1 = *(const short8*)&(LBn_)[boff2 + (1 << 9)];                      \
    }                                                                          \
    ST_;                                                                       \
    _Pragma("unroll")                                                          \
    for (int m = 0; m < 8; ++m) {                                              \
        MF16(acc[m][2], aHi[m], bHi2);                                         \
        MF16(acc[m][3], aHi[m], bHi3);                                         \
    }                                                                          \
    __builtin_amdgcn_s_setprio(0);

__global__ __launch_bounds__(512, 2)
void gemm_bt_8ph(const unsigned short* __restrict__ A,
                 const unsigned short* __restrict__ B,
                 float* __restrict__ C, int M, int N, int K, int lda, int ldc)
{
    __shared__ __attribute__((aligned(16))) unsigned short A0s[16384];
    __shared__ __attribute__((aligned(16))) unsigned short B0s[16384];
    __shared__ __attribute__((aligned(16))) unsigned short A1s[16384];
    __shared__ __attribute__((aligned(16))) unsigned short B1s[16384];
    const int tid = threadIdx.x;
    const int lane = tid & 63, wave = tid >> 6;
    const int quad = lane >> 4, l15 = lane & 15;
    const int wm = wave >> 2, wn = wave & 3;

    // split-K decode + bijective XCD swizzle (m204) within the split.
    const int Mt = M >> 8, Nt = N >> 8;
    const int tps = Mt * Nt;
    const int sk = blockIdx.x / tps, inner = blockIdx.x % tps;
    const int q = tps >> 3, r = tps & 7;
    const int xcd = inner & 7, idx = inner >> 3;
    const int wgid = (xcd < r ? xcd * (q + 1) : r * (q + 1) + (xcd - r) * q) + idx;
    const int mt = wgid % Mt, nt = wgid / Mt;
    const int m0 = mt << 8, n0 = nt << 8;

    const unsigned short* Ab = A + (size_t)sk * K;
    const unsigned short* Bb = B + (size_t)sk * K;
    float* Cb = C + (size_t)sk * (size_t)M * ldc;

    // hoisted per-thread staging addresses: rows rr0 and rr0+128, same chunk.
    const int rr0 = tid >> 2;
    const int lcx = (tid & 3) ^ ((rr0 >> 1) & 3);
    const unsigned short* aP = Ab + (size_t)(m0 + rr0) * lda + (lcx << 3);
    const unsigned short* bP = Bb + (size_t)(n0 + rr0) * lda + (lcx << 3);
    const size_t rstep = (size_t)lda << 7;              // +128 rows
    const int ldst = tid << 3;                          // LDS slot (shorts)

    auto stA = [&](unsigned short* arr, int t, int kh) {
        const int kb = (t << 6) + (kh << 5);
        gll16(aP + kb, arr + (kh << 13) + ldst);
        gll16(aP + rstep + kb, arr + (kh << 13) + ldst + 4096);
    };
    auto stB = [&](unsigned short* arr, int t, int kh) {
        const int kb = (t << 6) + (kh << 5);
        gll16(bP + kb, arr + (kh << 13) + ldst);
        gll16(bP + rstep + kb, arr + (kh << 13) + ldst + 4096);
    };

    floatx4 acc[8][4] = {};
    short8 aLo[8], aHi[8];
    short8 bLo0, bLo1, bLo2, bLo3, bHi0, bHi1, bHi2, bHi3;

    const int ph = quad ^ ((l15 >> 1) & 3);                // phys chunk on read
    const int aoff2 = ((wm << 7) + l15) * 32 + (ph << 3);  // shorts
    const int boff2 = ((wn << 6) + l15) * 32 + (ph << 3);

    // prologue: t0 full (8 gll), t1 {Akh0,Bkh0,Akh1} (6 gll); drain t0;
    // barrier; prefetch first-phase operands (between two barriers).
    stA(A0s, 0, 0); stB(B0s, 0, 0); stA(A0s, 0, 1); stB(B0s, 0, 1);
    stA(A1s, 1, 0); stB(B1s, 1, 0); stA(A1s, 1, 1);
    asm volatile("s_waitcnt vmcnt(6)" ::: "memory");
    __builtin_amdgcn_s_barrier();
#pragma unroll
    for (int m = 0; m < 8; ++m)
        aLo[m] = *(const short8*)&A0s[aoff2 + (m << 9)];
    bLo0 = *(const short8*)&B0s[boff2];
    bLo1 = *(const short8*)&B0s[boff2 + (1 << 9)];

    const int NITER = K >> 7;   // tile pairs
    for (int it = 0; it < NITER; ++it) {
        const int t = it << 1;
        const bool nl = (it + 1 < NITER);
        // group A: tile t (A0s,B0s); prefetches group B's ph1 in its ph4.
        PH1(B0s, stB(B1s, t + 1, 1));
        PH2(A0s, B0s, if (nl) stA(A0s, t + 2, 0));
        PH3(B0s, if (nl) stB(B0s, t + 2, 0),
            if (nl) asm volatile("s_waitcnt vmcnt(8)" ::: "memory");
            else    asm volatile("s_waitcnt vmcnt(4)" ::: "memory"));
        PH4(A1s, B1s, if (nl) stA(A0s, t + 2, 1), true);
        // group B: tile t+1 (A1s,B1s); prefetches next group A's ph1.
        PH1(B1s, if (nl) stB(B0s, t + 2, 1));
        PH2(A1s, B1s, if (nl) stA(A1s, t + 3, 0));
        PH3(B1s, if (nl) stB(B1s, t + 3, 0),
            if (nl) asm volatile("s_waitcnt vmcnt(8)" ::: "memory");
            else    asm volatile("s_waitcnt vmcnt(0)" ::: "memory"));
        PH4(A0s, B0s, if (nl) stA(A1s, t + 3, 1), nl);
    }
    asm volatile("s_waitcnt vmcnt(0)" ::: "memory");

#pragma unroll
    for (int m = 0; m < 8; ++m) {
        const int row = m0 + (wm << 7) + m * 16 + (quad << 2);
#pragma unroll
        for (int n = 0; n < 4; ++n) {
            const int col = n0 + (wn << 6) + n * 16 + l15;
#pragma unroll
            for (int rr = 0; rr < 4; ++rr)
                Cb[(size_t)(row + rr) * ldc + col] = acc[m][n][rr];
        }
    }
}

// ---------- out split-K reduce: out = P0+P1+P2+P3 ----------
__global__ __launch_bounds__(256)
void out_reduce4_k(const float* __restrict__ P, float* __restrict__ out)
{
    const size_t i = ((size_t)blockIdx.x * 256 + threadIdx.x) * 4;
    const size_t stride = (size_t)kS * kHID;
    float4 s0 = *(const float4*)&P[i];
    float4 s1 = *(const float4*)&P[i + stride];
    float4 s2 = *(const float4*)&P[i + 2 * stride];
    float4 s3 = *(const float4*)&P[i + 3 * stride];
    float4 o;
    o.x = s0.x + s1.x + s2.x + s3.x;
    o.y = s0.y + s1.y + s2.y + s3.y;
    o.z = s0.z + s1.z + s2.z + s3.z;
    o.w = s0.w + s1.w + s2.w + s3.w;
    *(float4*)&out[i] = o;
}

// ---------- strip GEMM (cols 8192..8511), split-K=4 -> partials ----------
__global__ __launch_bounds__(256)
void gemm_strip_sk(const unsigned short* __restrict__ A,
                   const unsigned short* __restrict__ B,
                   float* __restrict__ P, int K)
{
    __shared__ unsigned short As[128 * 64];
    __shared__ unsigned short Bs[128 * 64];
    const int bi = blockIdx.x;
    const int sk = bi / 48, rem = bi % 48, mt = rem / 3, nt = rem % 3;
    const int m0 = mt * 128, n0 = nt * 128, kbase = sk * 512;
    const int tid = threadIdx.x;
    const int lane = tid & 63, quad = lane >> 4, l15 = lane & 15;
    const int wave = tid >> 6;
    const int wm = (wave & 1) * 64, wn = (wave >> 1) * 64;

    floatx4 acc[4][4] = {};

    int rowS[4], lcS[4];
#pragma unroll
    for (int i = 0; i < 4; ++i) {
        int f = tid + 256 * i;
        rowS[i] = f >> 3;
        lcS[i] = ((f & 7) ^ (rowS[i] & 7)) * 8;
    }

    for (int kk = 0; kk < 512; kk += 64) {
        const int k0 = kbase + kk;
#pragma unroll
        for (int i = 0; i < 4; ++i) {
            int ra = m0 + rowS[i];
            gll16(&A[(size_t)ra * K + k0 + lcS[i]], &As[(size_t)(tid + 256 * i) * 8]);
        }
#pragma unroll
        for (int i = 0; i < 4; ++i) {
            int rb = n0 + rowS[i]; if (rb > 319) rb = 319;
            gll16(&B[(size_t)rb * K + k0 + lcS[i]], &Bs[(size_t)(tid + 256 * i) * 8]);
        }
        __syncthreads();

        short8 af[4][2], bf[4][2];
#pragma unroll
        for (int ks = 0; ks < 2; ++ks) {
            const int ph = ((ks * 4 + quad) ^ (l15 & 7)) * 8;
#pragma unroll
            for (int mi = 0; mi < 4; ++mi)
                af[mi][ks] = *(const short8*)&As[(size_t)(wm + mi * 16 + l15) * 64 + ph];
#pragma unroll
            for (int ni = 0; ni < 4; ++ni)
                bf[ni][ks] = *(const short8*)&Bs[(size_t)(wn + ni * 16 + l15) * 64 + ph];
        }
#pragma unroll
        for (int ks = 0; ks < 2; ++ks)
#pragma unroll
            for (int mi = 0; mi < 4; ++mi)
#pragma unroll
                for (int ni = 0; ni < 4; ++ni)
                    acc[mi][ni] = __builtin_amdgcn_mfma_f32_16x16x32_bf16(
                        af[mi][ks], bf[ni][ks], acc[mi][ni], 0, 0, 0);
        __syncthreads();
    }

    float* Po = P + (size_t)sk * kS * 320;
#pragma unroll
    for (int mi = 0; mi < 4; ++mi)
#pragma unroll
        for (int ni = 0; ni < 4; ++ni) {
            int col = n0 + wn + ni * 16 + l15;
            if (col < 320) {
#pragma unroll
                for (int r = 0; r < 4; ++r) {
                    int row = m0 + wm + mi * 16 + quad * 4 + r;
                    Po[(size_t)row * 320 + col] = acc[mi][ni][r];
                }
            }
        }
}

// ---------- strip reduce: proj[:,8192+n] = sum_sk P[sk] ----------
__global__ __launch_bounds__(256)
void strip_reduce_k(const float* __restrict__ P, float* __restrict__ proj)
{
    const size_t i = ((size_t)blockIdx.x * 256 + threadIdx.x) * 4;
    const size_t stride = (size_t)kS * 320;
    float4 s0 = *(const float4*)&P[i];
    float4 s1 = *(const float4*)&P[i + stride];
    float4 s2 = *(const float4*)&P[i + 2 * stride];
    float4 s3 = *(const float4*)&P[i + 3 * stride];
    float4 o;
    o.x = s0.x + s1.x + s2.x + s3.x;
    o.y = s0.y + s1.y + s2.y + s3.y;
    o.z = s0.z + s1.z + s2.z + s3.z;
    o.w = s0.w + s1.w + s2.w + s3.w;
    const int m = (int)(i / 320), n = (int)(i % 320);
    *(float4*)&proj[(size_t)m * kProj + 8192 + n] = o;
}

// ---------- conv+SiLU -> bf16 consumer layouts ----------
__global__ __launch_bounds__(256)
void conv_silu2_k(const float* __restrict__ proj, const float* __restrict__ cw,
                  const float* __restrict__ cb,
                  unsigned short* __restrict__ XT, unsigned short* __restrict__ Bg,
                  unsigned short* __restrict__ Btg, unsigned short* __restrict__ Cg)
{
    __shared__ __attribute__((aligned(16))) unsigned short T[64][264];
    const int bd = blockIdx.x % 68, bt = blockIdx.x / 68;
    const int d0 = bd * 64, t0 = bt * 256;
    const int tid = threadIdx.x;
    const int dl = tid & 63;
    const int d = d0 + dl;
    const float b0 = cb[d];
    const float w0 = cw[d * 4 + 0], w1 = cw[d * 4 + 1];
    const float w2 = cw[d * 4 + 2], w3 = cw[d * 4 + 3];
    for (int it = 0; it < 64; ++it) {
        int tl = it * 4 + (tid >> 6);
        int t = t0 + tl;
        const float* pc = &proj[(size_t)t * kProj + kI + d];
        float acc = b0 + w3 * pc[0];
        if (t >= 1) acc += w2 * pc[-(ptrdiff_t)kProj];
        if (t >= 2) acc += w1 * pc[-(ptrdiff_t)(2 * kProj)];
        if (t >= 3) acc += w0 * pc[-(ptrdiff_t)(3 * kProj)];
        T[dl][tl] = f2bf(siluf(acc));
    }
    __syncthreads();

    if (d0 < kI) {                       // X: XT[d][t], rows along t (coalesced)
        int row = tid >> 2, cg = (tid & 3) * 64;
#pragma unroll
        for (int j = 0; j < 8; ++j)
            *(ushort8v*)&XT[(size_t)(d0 + row) * kS + t0 + cg + j * 8] =
                *(const ushort8v*)&T[row][cg + j * 8];
    } else if (d0 < kI + kN) {           // B: Bt[n][t] + Bg[t][n]
        int n0 = d0 - kI;
        int row = tid >> 2, cg = (tid & 3) * 64;
#pragma unroll
        for (int j = 0; j < 8; ++j)
            *(ushort8v*)&Btg[(size_t)(n0 + row) * kS + t0 + cg + j * 8] =
                *(const ushort8v*)&T[row][cg + j * 8];
        for (int pass = 0; pass < 16; ++pass) {
            int tl = pass * 16 + (tid >> 4), nq = (tid & 15) * 4;
            ushort4 v = {T[nq][tl], T[nq + 1][tl], T[nq + 2][tl], T[nq + 3][tl]};
            *(ushort4*)&Bg[(size_t)(t0 + tl) * kN + n0 + nq] = v;
        }
    } else {                             // C: Cg[t][n]
        int n0 = d0 - (kI + kN);
        for (int pass = 0; pass < 16; ++pass) {
            int tl = pass * 16 + (tid >> 4), nq = (tid & 15) * 4;
            ushort4 v = {T[nq][tl], T[nq + 1][tl], T[nq + 2][tl], T[nq + 3][tl]};
            *(ushort4*)&Cg[(size_t)(t0 + tl) * kN + n0 + nq] = v;
        }
    }
}

// ---------- dt = softplus(proj_dt + bias); per-chunk cumsum(dt*A) ----------
__global__ __launch_bounds__(256)
void dt_cumsum_k(const float* __restrict__ proj, const float* __restrict__ dt_bias,
                 const float* __restrict__ A_log, float* __restrict__ dt,
                 float* __restrict__ acum)
{
    __shared__ float wsum[4];
    const int c = blockIdx.x >> 6, h = blockIdx.x & 63;
    const int l = threadIdx.x, t = c * kChunk + l;
    float a = -expf(A_log[h]);
    float z = proj[(size_t)t * kProj + kI + kConv + h] + dt_bias[h];
    float d = (z > 20.f) ? z : log1pf(expf(z));
    dt[t * kH + h] = d;
    float v = d * a;
    int lane = l & 63, w = l >> 6;
#pragma unroll
    for (int off = 1; off < 64; off <<= 1) {
        float u = __shfl_up(v, off);
        if (lane >= off) v += u;
    }
    if (lane == 63) wsum[w] = v;
    __syncthreads();
    float add = 0.f;
    for (int i = 0; i < w; ++i) add += wsum[i];
    acum[t * kH + h] = v + add;
}

// ---------- states (v2): bf16 MFMA. out[p][n] = sum_s Xw^T[p][s] Bt[n][s] ---
__global__ __launch_bounds__(256)
void states2_k(const unsigned short* __restrict__ XT,
               const unsigned short* __restrict__ Btg,
               const float* __restrict__ dt, const float* __restrict__ acum,
               float* __restrict__ states)
{
    __shared__ __attribute__((aligned(16))) unsigned short Aw[64 * 72];
    __shared__ __attribute__((aligned(16))) unsigned short Bs[128 * 64];
    __shared__ float Wl[256];
    const int c = blockIdx.x >> 6, h = blockIdx.x & 63;
    const int tid = threadIdx.x;
    const int wave = tid >> 6, lane = tid & 63;
    const int quad = lane >> 4, l15 = lane & 15;
    const float aend = acum[(size_t)(c * kChunk + 255) * kH + h];
    {
        int t = c * kChunk + tid;
        Wl[tid] = __expf(aend - acum[(size_t)t * kH + h]) * dt[(size_t)t * kH + h];
    }
    __syncthreads();

    floatx4 acc[4][2] = {};
    for (int lt = 0; lt < 4; ++lt) {
        const int s0 = c * kChunk + lt * 64;
#pragma unroll
        for (int i = 0; i < 2; ++i) {       // Aw[p][s] = XT * w, stride 72
            int f = tid + 256 * i;
            int p = f >> 3, sc = (f & 7) * 8;
            ushort8v xv = *(const ushort8v*)&XT[(size_t)(h * 64 + p) * kS + s0 + sc];
            ushort8v o;
#pragma unroll
            for (int j = 0; j < 8; ++j)
                o[j] = f2bf(bf2f(xv[j]) * Wl[lt * 64 + sc + j]);
            *(ushort8v*)&Aw[p * 72 + sc] = o;
        }
#pragma unroll
        for (int i = 0; i < 4; ++i) {       // Bs[n][s], phys chunk = lg ^ (n&7)
            int f = tid + 256 * i;
            int n = f >> 3, ph = f & 7, lg = ph ^ (n & 7);
            gll16(&Btg[(size_t)n * kS + s0 + lg * 8], &Bs[(size_t)f * 8]);
        }
        __syncthreads();
#pragma unroll
        for (int ks = 0; ks < 2; ++ks) {
            short8 bfr[2];
#pragma unroll
            for (int nj = 0; nj < 2; ++nj) {
                int n = (wave * 2 + nj) * 16 + l15;
                int ph = (ks * 4 + quad) ^ (n & 7);
                bfr[nj] = *(const short8*)&Bs[n * 64 + ph * 8];
            }
#pragma unroll
            for (int pi = 0; pi < 4; ++pi) {
                short8 af = *(const short8*)&Aw[(pi * 16 + l15) * 72 + ks * 32 + quad * 8];
                acc[pi][0] = __builtin_amdgcn_mfma_f32_16x16x32_bf16(af, bfr[0], acc[pi][0], 0, 0, 0);
                acc[pi][1] = __builtin_amdgcn_mfma_f32_16x16x32_bf16(af, bfr[1], acc[pi][1], 0, 0, 0);
            }
        }
        __syncthreads();
    }
    const size_t base = (size_t)(c * kH + h) * (kP * kN);
#pragma unroll
    for (int pi = 0; pi < 4; ++pi)
#pragma unroll
        for (int nj = 0; nj < 2; ++nj) {
            int n = (wave * 2 + nj) * 16 + l15;
#pragma unroll
            for (int r = 0; r < 4; ++r)
                states[base + (size_t)(pi * 16 + quad * 4 + r) * kN + n] = acc[pi][nj][r];
        }
}

// ---------- sequential inter-chunk recurrence ----------
__global__ __launch_bounds__(256)
void scan_k(const float* __restrict__ states, const float* __restrict__ acum,
            float* __restrict__ prev)
{
    const int h = blockIdx.x >> 3, seg = blockIdx.x & 7;
    const int e = (seg * 256 + threadIdx.x) * 4;
    float4 carry = make_float4(0.f, 0.f, 0.f, 0.f);
    for (int c = 0; c < kNC; ++c) {
        size_t base = (size_t)(c * kH + h) * (kP * kN);
        *(float4*)&prev[base + e] = carry;
        float dec = __expf(acum[(size_t)(c * kChunk + 255) * kH + h]);
        float4 st = *(const float4*)&states[base + e];
        carry.x = carry.x * dec + st.x; carry.y = carry.y * dec + st.y;
        carry.z = carry.z * dec + st.z; carry.w = carry.w * dec + st.w;
    }
}

// ---------- SSD Y (v4): gll16-staged bf16 tiles, XOR-swizzled ----------
__global__ __launch_bounds__(256)
void ssd_y4_k(const unsigned short* __restrict__ Cg,
              const unsigned short* __restrict__ Bg,
              const unsigned short* __restrict__ XT,
              const float* __restrict__ dt, const float* __restrict__ acum,
              const float* __restrict__ prev, const float* __restrict__ Dp,
              float* __restrict__ Y)
{
    __shared__ __attribute__((aligned(16))) unsigned short Cb[64 * 128];
    __shared__ __attribute__((aligned(16))) unsigned short Bb[64 * 128];
    __shared__ __attribute__((aligned(16))) unsigned short Xt[64 * 64];
    __shared__ __attribute__((aligned(16))) unsigned short Wb[64 * 72];
    __shared__ float At[64], Asv[64], Dtv[64];

    const int bi = blockIdx.x;
    const int ti = bi & 3, h = (bi >> 2) & 63, c = bi >> 8;
    const int tid = threadIdx.x;
    const int wave = tid >> 6, lane = tid & 63;
    const int quad = lane >> 4, l15 = lane & 15;
    const int trow0 = c * kChunk + ti * 64;
    const float Dh = Dp[h];

#pragma unroll
    for (int i = 0; i < 4; ++i) {
        int f = tid + 256 * i;
        int row = f >> 4, ph = f & 15, lg = ph ^ (row & 15);
        gll16(&Cg[(size_t)(trow0 + row) * kN + lg * 8], &Cb[(size_t)f * 8]);
    }
    const size_t pbase = (size_t)(c * kH + h) * (kP * kN);
#pragma unroll
    for (int r = 0; r < 8; ++r) {
        int f = tid + 256 * r;
        int row = f >> 5, c4 = (f & 31) * 4;          // 4 fp32 = half a 16B chunk
        float4 v = *(const float4*)&prev[pbase + (size_t)row * kN + c4];
        ushort4 u = {f2bf(v.x), f2bf(v.y), f2bf(v.z), f2bf(v.w)};
        int dst = row * 128 + ((((f & 31) >> 1) ^ (row & 15)) * 8) + (f & 1) * 4;
        *(ushort4*)&Bb[dst] = u;
    }
    if (tid < 64) At[tid] = acum[(size_t)(trow0 + tid) * kH + h];
    __syncthreads();

    floatx4 yacc[4] = {};
#pragma unroll
    for (int ks = 0; ks < 4; ++ks) {
        int cha = (ks * 4 + quad) ^ l15;
        short8 a = *(const short8*)&Cb[(wave * 16 + l15) * 128 + cha * 8];
#pragma unroll
        for (int ni = 0; ni < 4; ++ni) {
            short8 b = *(const short8*)&Bb[(ni * 16 + l15) * 128 + cha * 8];
            yacc[ni] = __builtin_amdgcn_mfma_f32_16x16x32_bf16(a, b, yacc[ni], 0, 0, 0);
        }
    }
    {
        float eAr[4];
#pragma unroll
        for (int r = 0; r < 4; ++r) eAr[r] = __expf(At[wave * 16 + quad * 4 + r]);
#pragma unroll
        for (int ni = 0; ni < 4; ++ni)
#pragma unroll
            for (int r = 0; r < 4; ++r) yacc[ni][r] *= eAr[r];
    }

    for (int si = 0; si <= ti; ++si) {
        const int srow0 = c * kChunk + si * 64;
        __syncthreads();
#pragma unroll
        for (int i = 0; i < 4; ++i) {       // B tile
            int f = tid + 256 * i;
            int row = f >> 4, ph = f & 15, lg = ph ^ (row & 15);
            gll16(&Bg[(size_t)(srow0 + row) * kN + lg * 8], &Bb[(size_t)f * 8]);
        }
#pragma unroll
        for (int i = 0; i < 2; ++i) {       // X^T tile [p][s]
            int f = tid + 256 * i;
            int p = f >> 3, ph = f & 7, lg = ph ^ (p & 7);
            gll16(&XT[(size_t)(h * 64 + p) * kS + srow0 + lg * 8], &Xt[(size_t)f * 8]);
        }
        if (tid < 64) {
            Asv[tid] = acum[(size_t)(srow0 + tid) * kH + h];
            Dtv[tid] = dt[(size_t)(srow0 + tid) * kH + h];
        }
        __syncthreads();

        floatx4 sacc[4] = {};
#pragma unroll
        for (int ks = 0; ks < 4; ++ks) {
            int cha = (ks * 4 + quad) ^ l15;
            short8 a = *(const short8*)&Cb[(wave * 16 + l15) * 128 + cha * 8];
#pragma unroll
            for (int ni = 0; ni < 4; ++ni) {
                short8 b = *(const short8*)&Bb[(ni * 16 + l15) * 128 + cha * 8];
                sacc[ni] = __builtin_amdgcn_mfma_f32_16x16x32_bf16(a, b, sacc[ni], 0, 0, 0);
            }
        }

        const bool diag = (si == ti);
#pragma unroll
        for (int ni = 0; ni < 4; ++ni) {
            int s_ = ni * 16 + l15;
            float as = Asv[s_], dts = Dtv[s_];
#pragma unroll
            for (int r = 0; r < 4; ++r) {
                int tl = wave * 16 + quad * 4 + r;
                float w = sacc[ni][r] * __expf(At[tl] - as) * dts;
                if (diag) {
                    if (s_ > tl) w = 0.f;
                    else if (s_ == tl) w += Dh;
                }
                Wb[tl * 72 + s_] = f2bf(w);
            }
        }
#pragma unroll
        for (int ks = 0; ks < 2; ++ks) {
            short8 aw = *(const short8*)&Wb[(wave * 16 + l15) * 72 + ks * 32 + quad * 8];
#pragma unroll
            for (int ni = 0; ni < 4; ++ni) {
                int ph = ((ks * 4 + quad) ^ (l15 & 7)) * 8;
                short8 xb = *(const short8*)&Xt[(ni * 16 + l15) * 64 + ph];
                yacc[ni] = __builtin_amdgcn_mfma_f32_16x16x32_bf16(aw, xb, yacc[ni], 0, 0, 0);
            }
        }
    }

#pragma unroll
    for (int ni = 0; ni < 4; ++ni)
#pragma unroll
        for (int r = 0; r < 4; ++r)
            Y[(size_t)(trow0 + wave * 16 + quad * 4 + r) * kI + h * kP + ni * 16 + l15]
                = yacc[ni][r];
}

// ---------- gated RMSNorm -> bf16 ----------
__global__ __launch_bounds__(256)
void rmsnorm_gate_k(const float* __restrict__ Y, const float* __restrict__ proj,
                    const float* __restrict__ nw, unsigned short* __restrict__ Yb)
{
    __shared__ float red[4];
    const int t = blockIdx.x, tid = threadIdx.x;
    const float* yrow = &Y[(size_t)t * kI];
    const float* grow = &proj[(size_t)t * kProj];
    float v[16];
    float ss = 0.f;
#pragma unroll
    for (int j = 0; j < 4; ++j) {
        int i = (tid + 256 * j) * 4;
        float4 y4 = *(const float4*)&yrow[i];
        float4 g4 = *(const float4*)&grow[i];
        float a = y4.x * siluf(g4.x), bq = y4.y * siluf(g4.y);
        float cq = y4.z * siluf(g4.z), d = y4.w * siluf(g4.w);
        v[j * 4 + 0] = a; v[j * 4 + 1] = bq; v[j * 4 + 2] = cq; v[j * 4 + 3] = d;
        ss += a * a + bq * bq + cq * cq + d * d;
    }
#pragma unroll
    for (int off = 32; off > 0; off >>= 1) ss += __shfl_down(ss, off);
    if ((tid & 63) == 0) red[tid >> 6] = ss;
    __syncthreads();
    float sum = red[0] + red[1] + red[2] + red[3];
    float rr = rsqrtf(sum * (1.f / kI) + kEps);
#pragma unroll
    for (int j = 0; j < 4; ++j) {
        int i = (tid + 256 * j) * 4;
        float4 w4 = *(const float4*)&nw[i];
        ushort4 o;
        o.x = f2bf(v[j * 4 + 0] * rr * w4.x);
        o.y = f2bf(v[j * 4 + 1] * rr * w4.y);
        o.z = f2bf(v[j * 4 + 2] * rr * w4.z);
        o.w = f2bf(v[j * 4 + 3] * rr * w4.w);
        *(ushort4*)&Yb[(size_t)t * kI + i] = o;
    }
}

extern "C" void kernel_launch(void* const* d_in, const int* in_sizes, int n_in,
                              void* d_out, int out_size, void* d_ws, size_t ws_size,
                              hipStream_t stream)
{
    const float* x       = (const float*)d_in[0];
    const float* W_in    = (const float*)d_in[1];
    const float* conv_w  = (const float*)d_in[2];
    const float* conv_b  = (const float*)d_in[3];
    const float* dt_bias = (const float*)d_in[4];
    const float* A_log   = (const float*)d_in[5];
    const float* Dp      = (const float*)d_in[6];
    const float* norm_w  = (const float*)d_in[7];
    const float* W_out   = (const float*)d_in[8];
    float* out = (float*)d_out;

    float* ws   = (float*)d_ws;
    float* proj = ws;                                       // 2048*8512 f
    unsigned short* XT  = (unsigned short*)(proj + (size_t)kS * kProj);  // 4096*2048
    unsigned short* Bg  = XT + (size_t)kI * kS;             // 2048*128
    unsigned short* Btg = Bg + (size_t)kS * kN;             // 128*2048
    unsigned short* Cg  = Btg + (size_t)kN * kS;            // 2048*128
    float* dtb  = (float*)(Cg + (size_t)kS * kN);           // 2048*64
    float* acum = dtb + (size_t)kS * kH;                    // 2048*64
    float* prev = acum + (size_t)kS * kH;                   // 4,194,304 f
    float* Y    = prev + (size_t)kNC * kH * kP * kN;        // 8,388,608 f
    float* states = Y;
    unsigned short* xb  = XT;                               // early alias
    unsigned short* Wb  = (unsigned short*)prev;            // early (spans into Y)
    unsigned short* Yb  = (unsigned short*)prev;            // late
    unsigned short* Wob = XT;                               // late
    // strip partials: after Wb's float-equivalent footprint; inside prev+Y.
    float* Pstrip = prev + ((size_t)kProj * kHID) / 2;
    // out-GEMM partials: proj region (dead after rmsnorm reads the gate).
    float* Pout = proj;

    dim3 blk(256);
    const int kNmain = 8192;               // 32 x 256-col tiles -> 256 blocks
    cast_bf16_k<<<(kS * kHID) / 2048, blk, 0, stream>>>(x, xb);
    cast_bf16_k<<<(kProj * kHID) / 2048, blk, 0, stream>>>(W_in, Wb);
    gemm_bt_8ph<<<(kS >> 8) * (kNmain >> 8), dim3(512), 0, stream>>>(
        xb, Wb, proj, kS, kNmain, kHID, kHID, kProj);
    gemm_strip_sk<<<192, blk, 0, stream>>>(
        xb, Wb + (size_t)kNmain * kHID, Pstrip, kHID);
    strip_reduce_k<<<(kS * 320) / 1024, blk, 0, stream>>>(Pstrip, proj);
    conv_silu2_k<<<68 * 8, blk, 0, stream>>>(proj, conv_w, conv_b, XT, Bg, Btg, Cg);
    dt_cumsum_k<<<kNC * kH, blk, 0, stream>>>(proj, dt_bias, A_log, dtb, acum);
    states2_k<<<kNC * kH, blk, 0, stream>>>(XT, Btg, dtb, acum, states);
    scan_k<<<kH * 8, blk, 0, stream>>>(states, acum, prev);
    ssd_y4_k<<<kNC * kH * 4, blk, 0, stream>>>(Cg, Bg, XT, dtb, acum, prev, Dp, Y);
    rmsnorm_gate_k<<<kS, blk, 0, stream>>>(Y, proj, norm_w, Yb);
    cast_bf16_k<<<(kHID * kI) / 2048, blk, 0, stream>>>(W_out, Wob);
    // out GEMM: pipelined 8-phase 256^2, split-K=4 (grid 4*64), K=1024 each.
    gemm_bt_8ph<<<4 * (kS >> 8) * (kHID >> 8), dim3(512), 0, stream>>>(
        Yb, Wob, Pout, kS, kHID, kHID / 2, kI, kHID);
    out_reduce4_k<<<(kS * kHID) / 1024, blk, 0, stream>>>(Pout, out);
}

// Round 8
// 429.308 us; speedup vs baseline: 1.2952x; 1.2952x over previous
//
#include <hip/hip_runtime.h>
#include <math.h>

// Bamba-9B mixer, b=1 s=2048. Round 15: in-phase overlapped 8-phase GEMM.
//  - Round-13/14 post-mortem: phase-ahead register prefetch needs ~290 regs
//    (acc 128 AGPR + 96 frag + addr) > 256/wave budget at 8 waves/block ->
//    spill no matter the launch-bounds hint (VGPR stuck at 128, WRITE 249MB).
//  - This round: reads issued INSIDE each phase right before their MFMAs,
//    NO lgkmcnt(0) — the compiler's fine-grained counted lgkm waits let the
//    MFMA cluster start while later reads drain, and the 2 waves/SIMD
//    co-issue LDS vs MFMA. Fragment liveness is intra-phase (~40 regs), so
//    no spill. One barrier per phase (4/tile, was 9). vmcnt(6) at group tail
//    BEFORE the next barrier (cross-wave staging order); tail-iteration
//    vmcnt(0) (fixes round-5's formally-racy vmcnt(4)). sched_barrier(0)
//    after each raw s_barrier prevents read hoisting.
// Everything else unchanged from round 12/14.
static constexpr int kS     = 2048;
static constexpr int kHID   = 2048;
static constexpr int kI     = 4096;
static constexpr int kH     = 64;
static constexpr int kP     = 64;
static constexpr int kN     = 128;
static constexpr int kConv  = 4352;   // I + 2*G*N
static constexpr int kProj  = 8512;   // I + CONV + H
static constexpr int kChunk = 256;
static constexpr int kNC    = 8;
static constexpr float kEps = 1e-5f;

typedef __attribute__((ext_vector_type(8))) short short8;            // bf16 frag
typedef __attribute__((ext_vector_type(8))) unsigned short ushort8v;
typedef __attribute__((ext_vector_type(4))) float floatx4;

__device__ __forceinline__ float siluf(float x) {
    return x / (1.f + __expf(-x));
}
__device__ __forceinline__ unsigned short f2bf(float f) {   // RNE, finite
    unsigned int u = __float_as_uint(f);
    return (unsigned short)((u + 0x7FFFu + ((u >> 16) & 1u)) >> 16);
}
__device__ __forceinline__ float bf2f(unsigned short u) {
    return __uint_as_float((unsigned int)u << 16);
}
__device__ __forceinline__ void gll16(const void* g, void* l) {
    __builtin_amdgcn_global_load_lds(
        (const __attribute__((address_space(1))) void*)g,
        (__attribute__((address_space(3))) void*)l, 16, 0, 0);
}

// ---------- fp32 -> bf16 cast, 8 elems/thread ----------
__global__ __launch_bounds__(256)
void cast_bf16_k(const float* __restrict__ in, unsigned short* __restrict__ out)
{
    size_t i = ((size_t)blockIdx.x * 256 + threadIdx.x) * 8;
    float4 a = *(const float4*)&in[i];
    float4 b = *(const float4*)&in[i + 4];
    ushort4 u0 = {f2bf(a.x), f2bf(a.y), f2bf(a.z), f2bf(a.w)};
    ushort4 u1 = {f2bf(b.x), f2bf(b.y), f2bf(b.z), f2bf(b.w)};
    *(ushort4*)&out[i] = u0;
    *(ushort4*)&out[i + 4] = u1;
}

// ---------- 256x256-tile 8-phase bf16 NT GEMM, split-K, in-phase overlap ---
// M%256==0, N%256==0, K%256==0. grid = nsplit*(M/256)*(N/256).
// Buffers: [2 kh][256 rows][32 shorts] per array. Per phase: {barrier;
// sched_barrier; prio1; this phase's ds_reads; this phase's gll16 stage;
// MFMA cluster (compiler-counted lgkm waits overlap reads with MFMA);
// prio0}. vmcnt(6) at group tail, before the next group's barrier.
#define MF16(acc_, a_, b_) \
    acc_ = __builtin_amdgcn_mfma_f32_16x16x32_bf16(a_, b_, acc_, 0, 0, 0)

#define PH_OPEN()                                              \
    __builtin_amdgcn_s_barrier();                              \
    __builtin_amdgcn_sched_barrier(0);                         \
    __builtin_amdgcn_s_setprio(1);

#define GROUP(LA, LB, S1, S2, S3, S4, VMTAIL)                                  \
    {                                                                          \
        short8 a0[8], a1[8], b0, b1, b2, b3;                                   \
        PH_OPEN();                                                             \
        _Pragma("unroll")                                                      \
        for (int m = 0; m < 8; ++m)                                            \
            a0[m] = *(const short8*)&(LA)[aoff2 + (m << 9)];                   \
        b0 = *(const short8*)&(LB)[boff2];                                     \
        b1 = *(const short8*)&(LB)[boff2 + (1 << 9)];                          \
        S1;                                                                    \
        _Pragma("unroll")                                                      \
        for (int m = 0; m < 8; ++m) {                                          \
            MF16(acc[m][0], a0[m], b0);                                        \
            MF16(acc[m][1], a0[m], b1);                                        \
        }                                                                      \
        __builtin_amdgcn_s_setprio(0);                                         \
        PH_OPEN();                                                             \
        b2 = *(const short8*)&(LB)[boff2 + (2 << 9)];                          \
        b3 = *(const short8*)&(LB)[boff2 + (3 << 9)];                          \
        S2;                                                                    \
        _Pragma("unroll")                                                      \
        for (int m = 0; m < 8; ++m) {                                          \
            MF16(acc[m][2], a0[m], b2);                                        \
            MF16(acc[m][3], a0[m], b3);                                        \
        }                                                                      \
        __builtin_amdgcn_s_setprio(0);                                         \
        PH_OPEN();                                                             \
        _Pragma("unroll")                                                      \
        for (int m = 0; m < 8; ++m)                                            \
            a1[m] = *(const short8*)&(LA)[8192 + aoff2 + (m << 9)];            \
        b0 = *(const short8*)&(LB)[8192 + boff2];                              \
        b1 = *(const short8*)&(LB)[8192 + boff2 + (1 << 9)];                   \
        S3;                                                                    \
        _Pragma("unroll")                                                      \
        for (int m = 0; m < 8; ++m) {                                          \
            MF16(acc[m][0], a1[m], b0);                                        \
            MF16(acc[m][1], a1[m], b1);                                        \
        }                                                                      \
        __builtin_amdgcn_s_setprio(0);                                         \
        PH_OPEN();                                                             \
        b2 = *(const short8*)&(LB)[8192 + boff2 + (2 << 9)];                   \
        b3 = *(const short8*)&(LB)[8192 + boff2 + (3 << 9)];                   \
        S4;                                                                    \
        _Pragma("unroll")                                                      \
        for (int m = 0; m < 8; ++m) {                                          \
            MF16(acc[m][2], a1[m], b2);                                        \
            MF16(acc[m][3], a1[m], b3);                                        \
        }                                                                      \
        __builtin_amdgcn_s_setprio(0);                                         \
        VMTAIL;                                                                \
    }

__global__ __launch_bounds__(512)
void gemm_bt_8ph(const unsigned short* __restrict__ A,
                 const unsigned short* __restrict__ B,
                 float* __restrict__ C, int M, int N, int K, int lda, int ldc)
{
    __shared__ __attribute__((aligned(16))) unsigned short A0s[16384];
    __shared__ __attribute__((aligned(16))) unsigned short B0s[16384];
    __shared__ __attribute__((aligned(16))) unsigned short A1s[16384];
    __shared__ __attribute__((aligned(16))) unsigned short B1s[16384];
    const int tid = threadIdx.x;
    const int lane = tid & 63, wave = tid >> 6;
    const int quad = lane >> 4, l15 = lane & 15;
    const int wm = wave >> 2, wn = wave & 3;

    // split-K decode + bijective XCD swizzle (m204) within the split.
    const int Mt = M >> 8, Nt = N >> 8;
    const int tps = Mt * Nt;
    const int sk = blockIdx.x / tps, inner = blockIdx.x % tps;
    const int q = tps >> 3, r = tps & 7;
    const int xcd = inner & 7, idx = inner >> 3;
    const int wgid = (xcd < r ? xcd * (q + 1) : r * (q + 1) + (xcd - r) * q) + idx;
    const int mt = wgid % Mt, nt = wgid / Mt;
    const int m0 = mt << 8, n0 = nt << 8;

    const unsigned short* Ab = A + (size_t)sk * K;
    const unsigned short* Bb = B + (size_t)sk * K;
    float* Cb = C + (size_t)sk * (size_t)M * ldc;

    // hoisted per-thread staging addresses: rows rr0 and rr0+128, same chunk.
    const int rr0 = tid >> 2;
    const int lcx = (tid & 3) ^ ((rr0 >> 1) & 3);
    const unsigned short* aP = Ab + (size_t)(m0 + rr0) * lda + (lcx << 3);
    const unsigned short* bP = Bb + (size_t)(n0 + rr0) * lda + (lcx << 3);
    const size_t rstep = (size_t)lda << 7;              // +128 rows
    const int ldst = tid << 3;                          // LDS slot (shorts)

    auto stA = [&](unsigned short* arr, int t, int kh) {
        const int kb = (t << 6) + (kh << 5);
        gll16(aP + kb, arr + (kh << 13) + ldst);
        gll16(aP + rstep + kb, arr + (kh << 13) + ldst + 4096);
    };
    auto stB = [&](unsigned short* arr, int t, int kh) {
        const int kb = (t << 6) + (kh << 5);
        gll16(bP + kb, arr + (kh << 13) + ldst);
        gll16(bP + rstep + kb, arr + (kh << 13) + ldst + 4096);
    };

    floatx4 acc[8][4] = {};

    const int ph = quad ^ ((l15 >> 1) & 3);                // phys chunk on read
    const int aoff2 = ((wm << 7) + l15) * 32 + (ph << 3);  // shorts
    const int boff2 = ((wn << 6) + l15) * 32 + (ph << 3);

    // prologue: t0 full (8 gll) then t1 {Akh0,Bkh0,Akh1} (6 gll); drain t0.
    stA(A0s, 0, 0); stB(B0s, 0, 0); stA(A0s, 0, 1); stB(B0s, 0, 1);
    stA(A1s, 1, 0); stB(B1s, 1, 0); stA(A1s, 1, 1);
    asm volatile("s_waitcnt vmcnt(6)" ::: "memory");

    const int NITER = K >> 7;   // tile pairs
    for (int it = 0; it < NITER; ++it) {
        const int t = it << 1;
        const bool nl = (it + 1 < NITER);
        // group A: tile t (A0s,B0s)
        GROUP(A0s, B0s,
              stB(B1s, t + 1, 1),
              if (nl) stA(A0s, t + 2, 0),
              if (nl) stB(B0s, t + 2, 0),
              if (nl) stA(A0s, t + 2, 1),
              if (nl) asm volatile("s_waitcnt vmcnt(6)" ::: "memory");
              else    asm volatile("s_waitcnt vmcnt(0)" ::: "memory"))
        // group B: tile t+1 (A1s,B1s)
        GROUP(A1s, B1s,
              if (nl) stB(B0s, t + 2, 1),
              if (nl) stA(A1s, t + 3, 0),
              if (nl) stB(B1s, t + 3, 0),
              if (nl) stA(A1s, t + 3, 1),
              if (nl) asm volatile("s_waitcnt vmcnt(6)" ::: "memory");
              else    asm volatile("s_waitcnt vmcnt(0)" ::: "memory"))
    }
    asm volatile("s_waitcnt vmcnt(0)" ::: "memory");

#pragma unroll
    for (int m = 0; m < 8; ++m) {
        const int row = m0 + (wm << 7) + m * 16 + (quad << 2);
#pragma unroll
        for (int n = 0; n < 4; ++n) {
            const int col = n0 + (wn << 6) + n * 16 + l15;
#pragma unroll
            for (int rr = 0; rr < 4; ++rr)
                Cb[(size_t)(row + rr) * ldc + col] = acc[m][n][rr];
        }
    }
}

// ---------- out split-K reduce: out = P0+P1+P2+P3 ----------
__global__ __launch_bounds__(256)
void out_reduce4_k(const float* __restrict__ P, float* __restrict__ out)
{
    const size_t i = ((size_t)blockIdx.x * 256 + threadIdx.x) * 4;
    const size_t stride = (size_t)kS * kHID;
    float4 s0 = *(const float4*)&P[i];
    float4 s1 = *(const float4*)&P[i + stride];
    float4 s2 = *(const float4*)&P[i + 2 * stride];
    float4 s3 = *(const float4*)&P[i + 3 * stride];
    float4 o;
    o.x = s0.x + s1.x + s2.x + s3.x;
    o.y = s0.y + s1.y + s2.y + s3.y;
    o.z = s0.z + s1.z + s2.z + s3.z;
    o.w = s0.w + s1.w + s2.w + s3.w;
    *(float4*)&out[i] = o;
}

// ---------- strip GEMM (cols 8192..8511), split-K=4 -> partials ----------
// grid: sk(4) x mt(16) x nt(3); B passed pre-offset to strip rows (320 rows).
__global__ __launch_bounds__(256)
void gemm_strip_sk(const unsigned short* __restrict__ A,
                   const unsigned short* __restrict__ B,
                   float* __restrict__ P, int K)
{
    __shared__ unsigned short As[128 * 64];
    __shared__ unsigned short Bs[128 * 64];
    const int bi = blockIdx.x;
    const int sk = bi / 48, rem = bi % 48, mt = rem / 3, nt = rem % 3;
    const int m0 = mt * 128, n0 = nt * 128, kbase = sk * 512;
    const int tid = threadIdx.x;
    const int lane = tid & 63, quad = lane >> 4, l15 = lane & 15;
    const int wave = tid >> 6;
    const int wm = (wave & 1) * 64, wn = (wave >> 1) * 64;

    floatx4 acc[4][4] = {};

    int rowS[4], lcS[4];
#pragma unroll
    for (int i = 0; i < 4; ++i) {
        int f = tid + 256 * i;
        rowS[i] = f >> 3;
        lcS[i] = ((f & 7) ^ (rowS[i] & 7)) * 8;
    }

    for (int kk = 0; kk < 512; kk += 64) {
        const int k0 = kbase + kk;
#pragma unroll
        for (int i = 0; i < 4; ++i) {
            int ra = m0 + rowS[i];
            gll16(&A[(size_t)ra * K + k0 + lcS[i]], &As[(size_t)(tid + 256 * i) * 8]);
        }
#pragma unroll
        for (int i = 0; i < 4; ++i) {
            int rb = n0 + rowS[i]; if (rb > 319) rb = 319;
            gll16(&B[(size_t)rb * K + k0 + lcS[i]], &Bs[(size_t)(tid + 256 * i) * 8]);
        }
        __syncthreads();

        short8 af[4][2], bf[4][2];
#pragma unroll
        for (int ks = 0; ks < 2; ++ks) {
            const int ph = ((ks * 4 + quad) ^ (l15 & 7)) * 8;
#pragma unroll
            for (int mi = 0; mi < 4; ++mi)
                af[mi][ks] = *(const short8*)&As[(size_t)(wm + mi * 16 + l15) * 64 + ph];
#pragma unroll
            for (int ni = 0; ni < 4; ++ni)
                bf[ni][ks] = *(const short8*)&Bs[(size_t)(wn + ni * 16 + l15) * 64 + ph];
        }
#pragma unroll
        for (int ks = 0; ks < 2; ++ks)
#pragma unroll
            for (int mi = 0; mi < 4; ++mi)
#pragma unroll
                for (int ni = 0; ni < 4; ++ni)
                    acc[mi][ni] = __builtin_amdgcn_mfma_f32_16x16x32_bf16(
                        af[mi][ks], bf[ni][ks], acc[mi][ni], 0, 0, 0);
        __syncthreads();
    }

    float* Po = P + (size_t)sk * kS * 320;
#pragma unroll
    for (int mi = 0; mi < 4; ++mi)
#pragma unroll
        for (int ni = 0; ni < 4; ++ni) {
            int col = n0 + wn + ni * 16 + l15;
            if (col < 320) {
#pragma unroll
                for (int r = 0; r < 4; ++r) {
                    int row = m0 + wm + mi * 16 + quad * 4 + r;
                    Po[(size_t)row * 320 + col] = acc[mi][ni][r];
                }
            }
        }
}

// ---------- strip reduce: proj[:,8192+n] = sum_sk P[sk] ----------
__global__ __launch_bounds__(256)
void strip_reduce_k(const float* __restrict__ P, float* __restrict__ proj)
{
    const size_t i = ((size_t)blockIdx.x * 256 + threadIdx.x) * 4;
    const size_t stride = (size_t)kS * 320;
    float4 s0 = *(const float4*)&P[i];
    float4 s1 = *(const float4*)&P[i + stride];
    float4 s2 = *(const float4*)&P[i + 2 * stride];
    float4 s3 = *(const float4*)&P[i + 3 * stride];
    float4 o;
    o.x = s0.x + s1.x + s2.x + s3.x;
    o.y = s0.y + s1.y + s2.y + s3.y;
    o.z = s0.z + s1.z + s2.z + s3.z;
    o.w = s0.w + s1.w + s2.w + s3.w;
    const int m = (int)(i / 320), n = (int)(i % 320);
    *(float4*)&proj[(size_t)m * kProj + 8192 + n] = o;
}

// ---------- conv+SiLU -> bf16 consumer layouts ----------
__global__ __launch_bounds__(256)
void conv_silu2_k(const float* __restrict__ proj, const float* __restrict__ cw,
                  const float* __restrict__ cb,
                  unsigned short* __restrict__ XT, unsigned short* __restrict__ Bg,
                  unsigned short* __restrict__ Btg, unsigned short* __restrict__ Cg)
{
    __shared__ __attribute__((aligned(16))) unsigned short T[64][264];
    const int bd = blockIdx.x % 68, bt = blockIdx.x / 68;
    const int d0 = bd * 64, t0 = bt * 256;
    const int tid = threadIdx.x;
    const int dl = tid & 63;
    const int d = d0 + dl;
    const float b0 = cb[d];
    const float w0 = cw[d * 4 + 0], w1 = cw[d * 4 + 1];
    const float w2 = cw[d * 4 + 2], w3 = cw[d * 4 + 3];
    for (int it = 0; it < 64; ++it) {
        int tl = it * 4 + (tid >> 6);
        int t = t0 + tl;
        const float* pc = &proj[(size_t)t * kProj + kI + d];
        float acc = b0 + w3 * pc[0];
        if (t >= 1) acc += w2 * pc[-(ptrdiff_t)kProj];
        if (t >= 2) acc += w1 * pc[-(ptrdiff_t)(2 * kProj)];
        if (t >= 3) acc += w0 * pc[-(ptrdiff_t)(3 * kProj)];
        T[dl][tl] = f2bf(siluf(acc));
    }
    __syncthreads();

    if (d0 < kI) {                       // X: XT[d][t], rows along t (coalesced)
        int row = tid >> 2, cg = (tid & 3) * 64;
#pragma unroll
        for (int j = 0; j < 8; ++j)
            *(ushort8v*)&XT[(size_t)(d0 + row) * kS + t0 + cg + j * 8] =
                *(const ushort8v*)&T[row][cg + j * 8];
    } else if (d0 < kI + kN) {           // B: Bt[n][t] + Bg[t][n]
        int n0 = d0 - kI;
        int row = tid >> 2, cg = (tid & 3) * 64;
#pragma unroll
        for (int j = 0; j < 8; ++j)
            *(ushort8v*)&Btg[(size_t)(n0 + row) * kS + t0 + cg + j * 8] =
                *(const ushort8v*)&T[row][cg + j * 8];
        for (int pass = 0; pass < 16; ++pass) {
            int tl = pass * 16 + (tid >> 4), nq = (tid & 15) * 4;
            ushort4 v = {T[nq][tl], T[nq + 1][tl], T[nq + 2][tl], T[nq + 3][tl]};
            *(ushort4*)&Bg[(size_t)(t0 + tl) * kN + n0 + nq] = v;
        }
    } else {                             // C: Cg[t][n]
        int n0 = d0 - (kI + kN);
        for (int pass = 0; pass < 16; ++pass) {
            int tl = pass * 16 + (tid >> 4), nq = (tid & 15) * 4;
            ushort4 v = {T[nq][tl], T[nq + 1][tl], T[nq + 2][tl], T[nq + 3][tl]};
            *(ushort4*)&Cg[(size_t)(t0 + tl) * kN + n0 + nq] = v;
        }
    }
}

// ---------- dt = softplus(proj_dt + bias); per-chunk cumsum(dt*A) ----------
__global__ __launch_bounds__(256)
void dt_cumsum_k(const float* __restrict__ proj, const float* __restrict__ dt_bias,
                 const float* __restrict__ A_log, float* __restrict__ dt,
                 float* __restrict__ acum)
{
    __shared__ float wsum[4];
    const int c = blockIdx.x >> 6, h = blockIdx.x & 63;
    const int l = threadIdx.x, t = c * kChunk + l;
    float a = -expf(A_log[h]);
    float z = proj[(size_t)t * kProj + kI + kConv + h] + dt_bias[h];
    float d = (z > 20.f) ? z : log1pf(expf(z));
    dt[t * kH + h] = d;
    float v = d * a;
    int lane = l & 63, w = l >> 6;
#pragma unroll
    for (int off = 1; off < 64; off <<= 1) {
        float u = __shfl_up(v, off);
        if (lane >= off) v += u;
    }
    if (lane == 63) wsum[w] = v;
    __syncthreads();
    float add = 0.f;
    for (int i = 0; i < w; ++i) add += wsum[i];
    acum[t * kH + h] = v + add;
}

// ---------- states (v2): bf16 MFMA. out[p][n] = sum_s Xw^T[p][s] Bt[n][s] ---
__global__ __launch_bounds__(256)
void states2_k(const unsigned short* __restrict__ XT,
               const unsigned short* __restrict__ Btg,
               const float* __restrict__ dt, const float* __restrict__ acum,
               float* __restrict__ states)
{
    __shared__ __attribute__((aligned(16))) unsigned short Aw[64 * 72];
    __shared__ __attribute__((aligned(16))) unsigned short Bs[128 * 64];
    __shared__ float Wl[256];
    const int c = blockIdx.x >> 6, h = blockIdx.x & 63;
    const int tid = threadIdx.x;
    const int wave = tid >> 6, lane = tid & 63;
    const int quad = lane >> 4, l15 = lane & 15;
    const float aend = acum[(size_t)(c * kChunk + 255) * kH + h];
    {
        int t = c * kChunk + tid;
        Wl[tid] = __expf(aend - acum[(size_t)t * kH + h]) * dt[(size_t)t * kH + h];
    }
    __syncthreads();

    floatx4 acc[4][2] = {};
    for (int lt = 0; lt < 4; ++lt) {
        const int s0 = c * kChunk + lt * 64;
#pragma unroll
        for (int i = 0; i < 2; ++i) {       // Aw[p][s] = XT * w, stride 72
            int f = tid + 256 * i;
            int p = f >> 3, sc = (f & 7) * 8;
            ushort8v xv = *(const ushort8v*)&XT[(size_t)(h * 64 + p) * kS + s0 + sc];
            ushort8v o;
#pragma unroll
            for (int j = 0; j < 8; ++j)
                o[j] = f2bf(bf2f(xv[j]) * Wl[lt * 64 + sc + j]);
            *(ushort8v*)&Aw[p * 72 + sc] = o;
        }
#pragma unroll
        for (int i = 0; i < 4; ++i) {       // Bs[n][s], phys chunk = lg ^ (n&7)
            int f = tid + 256 * i;
            int n = f >> 3, ph = f & 7, lg = ph ^ (n & 7);
            gll16(&Btg[(size_t)n * kS + s0 + lg * 8], &Bs[(size_t)f * 8]);
        }
        __syncthreads();
#pragma unroll
        for (int ks = 0; ks < 2; ++ks) {
            short8 bfr[2];
#pragma unroll
            for (int nj = 0; nj < 2; ++nj) {
                int n = (wave * 2 + nj) * 16 + l15;
                int ph = (ks * 4 + quad) ^ (n & 7);
                bfr[nj] = *(const short8*)&Bs[n * 64 + ph * 8];
            }
#pragma unroll
            for (int pi = 0; pi < 4; ++pi) {
                short8 af = *(const short8*)&Aw[(pi * 16 + l15) * 72 + ks * 32 + quad * 8];
                acc[pi][0] = __builtin_amdgcn_mfma_f32_16x16x32_bf16(af, bfr[0], acc[pi][0], 0, 0, 0);
                acc[pi][1] = __builtin_amdgcn_mfma_f32_16x16x32_bf16(af, bfr[1], acc[pi][1], 0, 0, 0);
            }
        }
        __syncthreads();
    }
    const size_t base = (size_t)(c * kH + h) * (kP * kN);
#pragma unroll
    for (int pi = 0; pi < 4; ++pi)
#pragma unroll
        for (int nj = 0; nj < 2; ++nj) {
            int n = (wave * 2 + nj) * 16 + l15;
#pragma unroll
            for (int r = 0; r < 4; ++r)
                states[base + (size_t)(pi * 16 + quad * 4 + r) * kN + n] = acc[pi][nj][r];
        }
}

// ---------- sequential inter-chunk recurrence ----------
__global__ __launch_bounds__(256)
void scan_k(const float* __restrict__ states, const float* __restrict__ acum,
            float* __restrict__ prev)
{
    const int h = blockIdx.x >> 3, seg = blockIdx.x & 7;
    const int e = (seg * 256 + threadIdx.x) * 4;
    float4 carry = make_float4(0.f, 0.f, 0.f, 0.f);
    for (int c = 0; c < kNC; ++c) {
        size_t base = (size_t)(c * kH + h) * (kP * kN);
        *(float4*)&prev[base + e] = carry;
        float dec = __expf(acum[(size_t)(c * kChunk + 255) * kH + h]);
        float4 st = *(const float4*)&states[base + e];
        carry.x = carry.x * dec + st.x; carry.y = carry.y * dec + st.y;
        carry.z = carry.z * dec + st.z; carry.w = carry.w * dec + st.w;
    }
}

// ---------- SSD Y (v4): gll16-staged bf16 tiles, XOR-swizzled ----------
__global__ __launch_bounds__(256)
void ssd_y4_k(const unsigned short* __restrict__ Cg,
              const unsigned short* __restrict__ Bg,
              const unsigned short* __restrict__ XT,
              const float* __restrict__ dt, const float* __restrict__ acum,
              const float* __restrict__ prev, const float* __restrict__ Dp,
              float* __restrict__ Y)
{
    __shared__ __attribute__((aligned(16))) unsigned short Cb[64 * 128];
    __shared__ __attribute__((aligned(16))) unsigned short Bb[64 * 128];
    __shared__ __attribute__((aligned(16))) unsigned short Xt[64 * 64];
    __shared__ __attribute__((aligned(16))) unsigned short Wb[64 * 72];
    __shared__ float At[64], Asv[64], Dtv[64];

    const int bi = blockIdx.x;
    const int ti = bi & 3, h = (bi >> 2) & 63, c = bi >> 8;
    const int tid = threadIdx.x;
    const int wave = tid >> 6, lane = tid & 63;
    const int quad = lane >> 4, l15 = lane & 15;
    const int trow0 = c * kChunk + ti * 64;
    const float Dh = Dp[h];

#pragma unroll
    for (int i = 0; i < 4; ++i) {
        int f = tid + 256 * i;
        int row = f >> 4, ph = f & 15, lg = ph ^ (row & 15);
        gll16(&Cg[(size_t)(trow0 + row) * kN + lg * 8], &Cb[(size_t)f * 8]);
    }
    const size_t pbase = (size_t)(c * kH + h) * (kP * kN);
#pragma unroll
    for (int r = 0; r < 8; ++r) {
        int f = tid + 256 * r;
        int row = f >> 5, c4 = (f & 31) * 4;          // 4 fp32 = half a 16B chunk
        float4 v = *(const float4*)&prev[pbase + (size_t)row * kN + c4];
        ushort4 u = {f2bf(v.x), f2bf(v.y), f2bf(v.z), f2bf(v.w)};
        int dst = row * 128 + ((((f & 31) >> 1) ^ (row & 15)) * 8) + (f & 1) * 4;
        *(ushort4*)&Bb[dst] = u;
    }
    if (tid < 64) At[tid] = acum[(size_t)(trow0 + tid) * kH + h];
    __syncthreads();

    floatx4 yacc[4] = {};
#pragma unroll
    for (int ks = 0; ks < 4; ++ks) {
        int cha = (ks * 4 + quad) ^ l15;
        short8 a = *(const short8*)&Cb[(wave * 16 + l15) * 128 + cha * 8];
#pragma unroll
        for (int ni = 0; ni < 4; ++ni) {
            short8 b = *(const short8*)&Bb[(ni * 16 + l15) * 128 + cha * 8];
            yacc[ni] = __builtin_amdgcn_mfma_f32_16x16x32_bf16(a, b, yacc[ni], 0, 0, 0);
        }
    }
    {
        float eAr[4];
#pragma unroll
        for (int r = 0; r < 4; ++r) eAr[r] = __expf(At[wave * 16 + quad * 4 + r]);
#pragma unroll
        for (int ni = 0; ni < 4; ++ni)
#pragma unroll
            for (int r = 0; r < 4; ++r) yacc[ni][r] *= eAr[r];
    }

    for (int si = 0; si <= ti; ++si) {
        const int srow0 = c * kChunk + si * 64;
        __syncthreads();
#pragma unroll
        for (int i = 0; i < 4; ++i) {       // B tile
            int f = tid + 256 * i;
            int row = f >> 4, ph = f & 15, lg = ph ^ (row & 15);
            gll16(&Bg[(size_t)(srow0 + row) * kN + lg * 8], &Bb[(size_t)f * 8]);
        }
#pragma unroll
        for (int i = 0; i < 2; ++i) {       // X^T tile [p][s]
            int f = tid + 256 * i;
            int p = f >> 3, ph = f & 7, lg = ph ^ (p & 7);
            gll16(&XT[(size_t)(h * 64 + p) * kS + srow0 + lg * 8], &Xt[(size_t)f * 8]);
        }
        if (tid < 64) {
            Asv[tid] = acum[(size_t)(srow0 + tid) * kH + h];
            Dtv[tid] = dt[(size_t)(srow0 + tid) * kH + h];
        }
        __syncthreads();

        floatx4 sacc[4] = {};
#pragma unroll
        for (int ks = 0; ks < 4; ++ks) {
            int cha = (ks * 4 + quad) ^ l15;
            short8 a = *(const short8*)&Cb[(wave * 16 + l15) * 128 + cha * 8];
#pragma unroll
            for (int ni = 0; ni < 4; ++ni) {
                short8 b = *(const short8*)&Bb[(ni * 16 + l15) * 128 + cha * 8];
                sacc[ni] = __builtin_amdgcn_mfma_f32_16x16x32_bf16(a, b, sacc[ni], 0, 0, 0);
            }
        }

        const bool diag = (si == ti);
#pragma unroll
        for (int ni = 0; ni < 4; ++ni) {
            int s_ = ni * 16 + l15;
            float as = Asv[s_], dts = Dtv[s_];
#pragma unroll
            for (int r = 0; r < 4; ++r) {
                int tl = wave * 16 + quad * 4 + r;
                float w = sacc[ni][r] * __expf(At[tl] - as) * dts;
                if (diag) {
                    if (s_ > tl) w = 0.f;
                    else if (s_ == tl) w += Dh;
                }
                Wb[tl * 72 + s_] = f2bf(w);
            }
        }
#pragma unroll
        for (int ks = 0; ks < 2; ++ks) {
            short8 aw = *(const short8*)&Wb[(wave * 16 + l15) * 72 + ks * 32 + quad * 8];
#pragma unroll
            for (int ni = 0; ni < 4; ++ni) {
                int ph = ((ks * 4 + quad) ^ (l15 & 7)) * 8;
                short8 xb = *(const short8*)&Xt[(ni * 16 + l15) * 64 + ph];
                yacc[ni] = __builtin_amdgcn_mfma_f32_16x16x32_bf16(aw, xb, yacc[ni], 0, 0, 0);
            }
        }
    }

#pragma unroll
    for (int ni = 0; ni < 4; ++ni)
#pragma unroll
        for (int r = 0; r < 4; ++r)
            Y[(size_t)(trow0 + wave * 16 + quad * 4 + r) * kI + h * kP + ni * 16 + l15]
                = yacc[ni][r];
}

// ---------- gated RMSNorm -> bf16 ----------
__global__ __launch_bounds__(256)
void rmsnorm_gate_k(const float* __restrict__ Y, const float* __restrict__ proj,
                    const float* __restrict__ nw, unsigned short* __restrict__ Yb)
{
    __shared__ float red[4];
    const int t = blockIdx.x, tid = threadIdx.x;
    const float* yrow = &Y[(size_t)t * kI];
    const float* grow = &proj[(size_t)t * kProj];
    float v[16];
    float ss = 0.f;
#pragma unroll
    for (int j = 0; j < 4; ++j) {
        int i = (tid + 256 * j) * 4;
        float4 y4 = *(const float4*)&yrow[i];
        float4 g4 = *(const float4*)&grow[i];
        float a = y4.x * siluf(g4.x), bq = y4.y * siluf(g4.y);
        float cq = y4.z * siluf(g4.z), d = y4.w * siluf(g4.w);
        v[j * 4 + 0] = a; v[j * 4 + 1] = bq; v[j * 4 + 2] = cq; v[j * 4 + 3] = d;
        ss += a * a + bq * bq + cq * cq + d * d;
    }
#pragma unroll
    for (int off = 32; off > 0; off >>= 1) ss += __shfl_down(ss, off);
    if ((tid & 63) == 0) red[tid >> 6] = ss;
    __syncthreads();
    float sum = red[0] + red[1] + red[2] + red[3];
    float rr = rsqrtf(sum * (1.f / kI) + kEps);
#pragma unroll
    for (int j = 0; j < 4; ++j) {
        int i = (tid + 256 * j) * 4;
        float4 w4 = *(const float4*)&nw[i];
        ushort4 o;
        o.x = f2bf(v[j * 4 + 0] * rr * w4.x);
        o.y = f2bf(v[j * 4 + 1] * rr * w4.y);
        o.z = f2bf(v[j * 4 + 2] * rr * w4.z);
        o.w = f2bf(v[j * 4 + 3] * rr * w4.w);
        *(ushort4*)&Yb[(size_t)t * kI + i] = o;
    }
}

extern "C" void kernel_launch(void* const* d_in, const int* in_sizes, int n_in,
                              void* d_out, int out_size, void* d_ws, size_t ws_size,
                              hipStream_t stream)
{
    const float* x       = (const float*)d_in[0];
    const float* W_in    = (const float*)d_in[1];
    const float* conv_w  = (const float*)d_in[2];
    const float* conv_b  = (const float*)d_in[3];
    const float* dt_bias = (const float*)d_in[4];
    const float* A_log   = (const float*)d_in[5];
    const float* Dp      = (const float*)d_in[6];
    const float* norm_w  = (const float*)d_in[7];
    const float* W_out   = (const float*)d_in[8];
    float* out = (float*)d_out;

    float* ws   = (float*)d_ws;
    float* proj = ws;                                       // 2048*8512 f
    unsigned short* XT  = (unsigned short*)(proj + (size_t)kS * kProj);  // 4096*2048
    unsigned short* Bg  = XT + (size_t)kI * kS;             // 2048*128
    unsigned short* Btg = Bg + (size_t)kS * kN;             // 128*2048
    unsigned short* Cg  = Btg + (size_t)kN * kS;            // 2048*128
    float* dtb  = (float*)(Cg + (size_t)kS * kN);           // 2048*64
    float* acum = dtb + (size_t)kS * kH;                    // 2048*64
    float* prev = acum + (size_t)kS * kH;                   // 4,194,304 f
    float* Y    = prev + (size_t)kNC * kH * kP * kN;        // 8,388,608 f
    float* states = Y;
    unsigned short* xb  = XT;                               // early alias
    unsigned short* Wb  = (unsigned short*)prev;            // early (spans into Y)
    unsigned short* Yb  = (unsigned short*)prev;            // late
    unsigned short* Wob = XT;                               // late
    // strip partials: after Wb's float-equivalent footprint; inside prev+Y.
    float* Pstrip = prev + ((size_t)kProj * kHID) / 2;
    // out-GEMM partials: proj region (dead after rmsnorm reads the gate).
    float* Pout = proj;

    dim3 blk(256);
    const int kNmain = 8192;               // 32 x 256-col tiles -> 256 blocks
    cast_bf16_k<<<(kS * kHID) / 2048, blk, 0, stream>>>(x, xb);
    cast_bf16_k<<<(kProj * kHID) / 2048, blk, 0, stream>>>(W_in, Wb);
    gemm_bt_8ph<<<(kS >> 8) * (kNmain >> 8), dim3(512), 0, stream>>>(
        xb, Wb, proj, kS, kNmain, kHID, kHID, kProj);
    gemm_strip_sk<<<192, blk, 0, stream>>>(
        xb, Wb + (size_t)kNmain * kHID, Pstrip, kHID);
    strip_reduce_k<<<(kS * 320) / 1024, blk, 0, stream>>>(Pstrip, proj);
    conv_silu2_k<<<68 * 8, blk, 0, stream>>>(proj, conv_w, conv_b, XT, Bg, Btg, Cg);
    dt_cumsum_k<<<kNC * kH, blk, 0, stream>>>(proj, dt_bias, A_log, dtb, acum);
    states2_k<<<kNC * kH, blk, 0, stream>>>(XT, Btg, dtb, acum, states);
    scan_k<<<kH * 8, blk, 0, stream>>>(states, acum, prev);
    ssd_y4_k<<<kNC * kH * 4, blk, 0, stream>>>(Cg, Bg, XT, dtb, acum, prev, Dp, Y);
    rmsnorm_gate_k<<<kS, blk, 0, stream>>>(Y, proj, norm_w, Yb);
    cast_bf16_k<<<(kHID * kI) / 2048, blk, 0, stream>>>(W_out, Wob);
    // out GEMM: 8-phase 256^2, split-K=4 (grid 4*64), K=1024 per block.
    gemm_bt_8ph<<<4 * (kS >> 8) * (kHID >> 8), dim3(512), 0, stream>>>(
        Yb, Wob, Pout, kS, kHID, kHID / 2, kI, kHID);
    out_reduce4_k<<<(kS * kHID) / 1024, blk, 0, stream>>>(Pout, out);
}

// Round 9
// 424.286 us; speedup vs baseline: 1.3105x; 1.0118x over previous
//
#include <hip/hip_runtime.h>
#include <math.h>

// Bamba-9B mixer, b=1 s=2048. Round 16: merge 8ph GEMM to 2 phases per K-tile.
//  - Round-15 accounting: 5250 cyc/K-tile vs 2483 MFMA floor; overhead = 4
//    barriers/tile + ~230cyc read preamble per 16-MFMA phase, lockstep waves.
//  - This round: 2 phases/tile (32 MFMA, 12 ds_reads each). Stage schedule:
//    2 units/phase; each buffer region overwritten exactly 1 phase after its
//    last read (reader MFMAs consume before the phase-end barrier); each
//    region consumed exactly 3 phases after staging -> UNIFORM vmcnt(8) at
//    every phase end (tail: vmcnt(0) at gamma-end of last iter covers
//    alpha(last)'s stage). Prologue 12 gll + vmcnt(8) matches steady state.
//  - Fragment liveness intra-phase (12 frags = 48 VGPR) -> no spill.
// Everything else unchanged from round 15.
static constexpr int kS     = 2048;
static constexpr int kHID   = 2048;
static constexpr int kI     = 4096;
static constexpr int kH     = 64;
static constexpr int kP     = 64;
static constexpr int kN     = 128;
static constexpr int kConv  = 4352;   // I + 2*G*N
static constexpr int kProj  = 8512;   // I + CONV + H
static constexpr int kChunk = 256;
static constexpr int kNC    = 8;
static constexpr float kEps = 1e-5f;

typedef __attribute__((ext_vector_type(8))) short short8;            // bf16 frag
typedef __attribute__((ext_vector_type(8))) unsigned short ushort8v;
typedef __attribute__((ext_vector_type(4))) float floatx4;

__device__ __forceinline__ float siluf(float x) {
    return x / (1.f + __expf(-x));
}
__device__ __forceinline__ unsigned short f2bf(float f) {   // RNE, finite
    unsigned int u = __float_as_uint(f);
    return (unsigned short)((u + 0x7FFFu + ((u >> 16) & 1u)) >> 16);
}
__device__ __forceinline__ float bf2f(unsigned short u) {
    return __uint_as_float((unsigned int)u << 16);
}
__device__ __forceinline__ void gll16(const void* g, void* l) {
    __builtin_amdgcn_global_load_lds(
        (const __attribute__((address_space(1))) void*)g,
        (__attribute__((address_space(3))) void*)l, 16, 0, 0);
}

// ---------- fp32 -> bf16 cast, 8 elems/thread ----------
__global__ __launch_bounds__(256)
void cast_bf16_k(const float* __restrict__ in, unsigned short* __restrict__ out)
{
    size_t i = ((size_t)blockIdx.x * 256 + threadIdx.x) * 8;
    float4 a = *(const float4*)&in[i];
    float4 b = *(const float4*)&in[i + 4];
    ushort4 u0 = {f2bf(a.x), f2bf(a.y), f2bf(a.z), f2bf(a.w)};
    ushort4 u1 = {f2bf(b.x), f2bf(b.y), f2bf(b.z), f2bf(b.w)};
    *(ushort4*)&out[i] = u0;
    *(ushort4*)&out[i + 4] = u1;
}

// ---------- 256x256-tile 2-phase/K-tile bf16 NT GEMM, split-K ----------
// M%256==0, N%256==0, K%256==0. grid = nsplit*(M/256)*(N/256).
// Buffers: [2 kh][256 rows][32 shorts] per array. Per phase: {barrier;
// sched_barrier; prio1; 12 ds_reads (4 B + 8 A); 2 stage-units (4 gll16);
// 32 MFMA (compiler-counted lgkm waits overlap reads with MFMA); prio0;
// vmcnt(8)}. Steady state: region staged in phase P is read in P+3;
// vmcnt(8) at P-end completes stages <= P-2. Overwrites trail last-read by
// exactly one phase (reader MFMAs consume reads before the phase-end
// barrier). Tail: vmcnt(0) at gamma-end of the last iteration.
#define MF16(acc_, a_, b_) \
    acc_ = __builtin_amdgcn_mfma_f32_16x16x32_bf16(a_, b_, acc_, 0, 0, 0)

#define VM8 asm volatile("s_waitcnt vmcnt(8)" ::: "memory")
#define VM0 asm volatile("s_waitcnt vmcnt(0)" ::: "memory")

#define PHASE(LA_, LB_, KH_, ST_, VM_)                                         \
    {                                                                          \
        __builtin_amdgcn_s_barrier();                                          \
        __builtin_amdgcn_sched_barrier(0);                                     \
        __builtin_amdgcn_s_setprio(1);                                         \
        short8 bf0 = *(const short8*)&(LB_)[(KH_) + boff2];                    \
        short8 bf1 = *(const short8*)&(LB_)[(KH_) + boff2 + (1 << 9)];         \
        short8 bf2 = *(const short8*)&(LB_)[(KH_) + boff2 + (2 << 9)];         \
        short8 bf3 = *(const short8*)&(LB_)[(KH_) + boff2 + (3 << 9)];         \
        short8 af[8];                                                          \
        _Pragma("unroll")                                                      \
        for (int m = 0; m < 8; ++m)                                            \
            af[m] = *(const short8*)&(LA_)[(KH_) + aoff2 + (m << 9)];          \
        ST_;                                                                   \
        _Pragma("unroll")                                                      \
        for (int m = 0; m < 8; ++m) {                                          \
            MF16(acc[m][0], af[m], bf0);                                       \
            MF16(acc[m][1], af[m], bf1);                                       \
            MF16(acc[m][2], af[m], bf2);                                       \
            MF16(acc[m][3], af[m], bf3);                                       \
        }                                                                      \
        __builtin_amdgcn_s_setprio(0);                                         \
        VM_;                                                                   \
    }

__global__ __launch_bounds__(512)
void gemm_bt_8ph(const unsigned short* __restrict__ A,
                 const unsigned short* __restrict__ B,
                 float* __restrict__ C, int M, int N, int K, int lda, int ldc)
{
    __shared__ __attribute__((aligned(16))) unsigned short A0s[16384];
    __shared__ __attribute__((aligned(16))) unsigned short B0s[16384];
    __shared__ __attribute__((aligned(16))) unsigned short A1s[16384];
    __shared__ __attribute__((aligned(16))) unsigned short B1s[16384];
    const int tid = threadIdx.x;
    const int lane = tid & 63, wave = tid >> 6;
    const int quad = lane >> 4, l15 = lane & 15;
    const int wm = wave >> 2, wn = wave & 3;

    // split-K decode + bijective XCD swizzle (m204) within the split.
    const int Mt = M >> 8, Nt = N >> 8;
    const int tps = Mt * Nt;
    const int sk = blockIdx.x / tps, inner = blockIdx.x % tps;
    const int q = tps >> 3, r = tps & 7;
    const int xcd = inner & 7, idx = inner >> 3;
    const int wgid = (xcd < r ? xcd * (q + 1) : r * (q + 1) + (xcd - r) * q) + idx;
    const int mt = wgid % Mt, nt = wgid / Mt;
    const int m0 = mt << 8, n0 = nt << 8;

    const unsigned short* Ab = A + (size_t)sk * K;
    const unsigned short* Bb = B + (size_t)sk * K;
    float* Cb = C + (size_t)sk * (size_t)M * ldc;

    // hoisted per-thread staging addresses: rows rr0 and rr0+128, same chunk.
    const int rr0 = tid >> 2;
    const int lcx = (tid & 3) ^ ((rr0 >> 1) & 3);
    const unsigned short* aP = Ab + (size_t)(m0 + rr0) * lda + (lcx << 3);
    const unsigned short* bP = Bb + (size_t)(n0 + rr0) * lda + (lcx << 3);
    const size_t rstep = (size_t)lda << 7;              // +128 rows
    const int ldst = tid << 3;                          // LDS slot (shorts)

    auto stA = [&](unsigned short* arr, int t, int kh) {
        const int kb = (t << 6) + (kh << 5);
        gll16(aP + kb, arr + (kh << 13) + ldst);
        gll16(aP + rstep + kb, arr + (kh << 13) + ldst + 4096);
    };
    auto stB = [&](unsigned short* arr, int t, int kh) {
        const int kb = (t << 6) + (kh << 5);
        gll16(bP + kb, arr + (kh << 13) + ldst);
        gll16(bP + rstep + kb, arr + (kh << 13) + ldst + 4096);
    };

    floatx4 acc[8][4] = {};

    const int ph = quad ^ ((l15 >> 1) & 3);                // phys chunk on read
    const int aoff2 = ((wm << 7) + l15) * 32 + (ph << 3);  // shorts
    const int boff2 = ((wn << 6) + l15) * 32 + (ph << 3);

    // prologue: t0 both kh (8 gll), t1 kh0 (4 gll); vmcnt(8) completes t0.kh0
    // (first 4) -- same invariant as the steady-state phase end.
    stA(A0s, 0, 0); stB(B0s, 0, 0); stA(A0s, 0, 1); stB(B0s, 0, 1);
    stA(A1s, 1, 0); stB(B1s, 1, 0);
    VM8;

    const int NITER = K >> 7;   // tile pairs
    for (int it = 0; it < NITER; ++it) {
        const int t = it << 1;
        const bool nl = (it + 1 < NITER);
        // alpha: tile t kh0; stage (A1s,B1s)[t+1].kh1 (read in delta).
        PHASE(A0s, B0s, 0,
              { stA(A1s, t + 1, 1); stB(B1s, t + 1, 1); },
              VM8)
        // beta: tile t kh1; stage (A0s,B0s)[t+2].kh0 (read next alpha).
        PHASE(A0s, B0s, 8192,
              if (nl) { stA(A0s, t + 2, 0); stB(B0s, t + 2, 0); },
              VM8)
        // gamma: tile t+1 kh0; stage (A0s,B0s)[t+2].kh1 (read next beta).
        PHASE(A1s, B1s, 0,
              if (nl) { stA(A0s, t + 2, 1); stB(B0s, t + 2, 1); },
              if (nl) { VM8; } else { VM0; })
        // delta: tile t+1 kh1; stage (A1s,B1s)[t+3].kh0 (read next gamma).
        PHASE(A1s, B1s, 8192,
              if (nl) { stA(A1s, t + 3, 0); stB(B1s, t + 3, 0); },
              VM8)
    }
    VM0;

#pragma unroll
    for (int m = 0; m < 8; ++m) {
        const int row = m0 + (wm << 7) + m * 16 + (quad << 2);
#pragma unroll
        for (int n = 0; n < 4; ++n) {
            const int col = n0 + (wn << 6) + n * 16 + l15;
#pragma unroll
            for (int rr = 0; rr < 4; ++rr)
                Cb[(size_t)(row + rr) * ldc + col] = acc[m][n][rr];
        }
    }
}

// ---------- out split-K reduce: out = P0+P1+P2+P3 ----------
__global__ __launch_bounds__(256)
void out_reduce4_k(const float* __restrict__ P, float* __restrict__ out)
{
    const size_t i = ((size_t)blockIdx.x * 256 + threadIdx.x) * 4;
    const size_t stride = (size_t)kS * kHID;
    float4 s0 = *(const float4*)&P[i];
    float4 s1 = *(const float4*)&P[i + stride];
    float4 s2 = *(const float4*)&P[i + 2 * stride];
    float4 s3 = *(const float4*)&P[i + 3 * stride];
    float4 o;
    o.x = s0.x + s1.x + s2.x + s3.x;
    o.y = s0.y + s1.y + s2.y + s3.y;
    o.z = s0.z + s1.z + s2.z + s3.z;
    o.w = s0.w + s1.w + s2.w + s3.w;
    *(float4*)&out[i] = o;
}

// ---------- strip GEMM (cols 8192..8511), split-K=4 -> partials ----------
// grid: sk(4) x mt(16) x nt(3); B passed pre-offset to strip rows (320 rows).
__global__ __launch_bounds__(256)
void gemm_strip_sk(const unsigned short* __restrict__ A,
                   const unsigned short* __restrict__ B,
                   float* __restrict__ P, int K)
{
    __shared__ unsigned short As[128 * 64];
    __shared__ unsigned short Bs[128 * 64];
    const int bi = blockIdx.x;
    const int sk = bi / 48, rem = bi % 48, mt = rem / 3, nt = rem % 3;
    const int m0 = mt * 128, n0 = nt * 128, kbase = sk * 512;
    const int tid = threadIdx.x;
    const int lane = tid & 63, quad = lane >> 4, l15 = lane & 15;
    const int wave = tid >> 6;
    const int wm = (wave & 1) * 64, wn = (wave >> 1) * 64;

    floatx4 acc[4][4] = {};

    int rowS[4], lcS[4];
#pragma unroll
    for (int i = 0; i < 4; ++i) {
        int f = tid + 256 * i;
        rowS[i] = f >> 3;
        lcS[i] = ((f & 7) ^ (rowS[i] & 7)) * 8;
    }

    for (int kk = 0; kk < 512; kk += 64) {
        const int k0 = kbase + kk;
#pragma unroll
        for (int i = 0; i < 4; ++i) {
            int ra = m0 + rowS[i];
            gll16(&A[(size_t)ra * K + k0 + lcS[i]], &As[(size_t)(tid + 256 * i) * 8]);
        }
#pragma unroll
        for (int i = 0; i < 4; ++i) {
            int rb = n0 + rowS[i]; if (rb > 319) rb = 319;
            gll16(&B[(size_t)rb * K + k0 + lcS[i]], &Bs[(size_t)(tid + 256 * i) * 8]);
        }
        __syncthreads();

        short8 af[4][2], bf[4][2];
#pragma unroll
        for (int ks = 0; ks < 2; ++ks) {
            const int ph = ((ks * 4 + quad) ^ (l15 & 7)) * 8;
#pragma unroll
            for (int mi = 0; mi < 4; ++mi)
                af[mi][ks] = *(const short8*)&As[(size_t)(wm + mi * 16 + l15) * 64 + ph];
#pragma unroll
            for (int ni = 0; ni < 4; ++ni)
                bf[ni][ks] = *(const short8*)&Bs[(size_t)(wn + ni * 16 + l15) * 64 + ph];
        }
#pragma unroll
        for (int ks = 0; ks < 2; ++ks)
#pragma unroll
            for (int mi = 0; mi < 4; ++mi)
#pragma unroll
                for (int ni = 0; ni < 4; ++ni)
                    acc[mi][ni] = __builtin_amdgcn_mfma_f32_16x16x32_bf16(
                        af[mi][ks], bf[ni][ks], acc[mi][ni], 0, 0, 0);
        __syncthreads();
    }

    float* Po = P + (size_t)sk * kS * 320;
#pragma unroll
    for (int mi = 0; mi < 4; ++mi)
#pragma unroll
        for (int ni = 0; ni < 4; ++ni) {
            int col = n0 + wn + ni * 16 + l15;
            if (col < 320) {
#pragma unroll
                for (int r = 0; r < 4; ++r) {
                    int row = m0 + wm + mi * 16 + quad * 4 + r;
                    Po[(size_t)row * 320 + col] = acc[mi][ni][r];
                }
            }
        }
}

// ---------- strip reduce: proj[:,8192+n] = sum_sk P[sk] ----------
__global__ __launch_bounds__(256)
void strip_reduce_k(const float* __restrict__ P, float* __restrict__ proj)
{
    const size_t i = ((size_t)blockIdx.x * 256 + threadIdx.x) * 4;
    const size_t stride = (size_t)kS * 320;
    float4 s0 = *(const float4*)&P[i];
    float4 s1 = *(const float4*)&P[i + stride];
    float4 s2 = *(const float4*)&P[i + 2 * stride];
    float4 s3 = *(const float4*)&P[i + 3 * stride];
    float4 o;
    o.x = s0.x + s1.x + s2.x + s3.x;
    o.y = s0.y + s1.y + s2.y + s3.y;
    o.z = s0.z + s1.z + s2.z + s3.z;
    o.w = s0.w + s1.w + s2.w + s3.w;
    const int m = (int)(i / 320), n = (int)(i % 320);
    *(float4*)&proj[(size_t)m * kProj + 8192 + n] = o;
}

// ---------- conv+SiLU -> bf16 consumer layouts ----------
__global__ __launch_bounds__(256)
void conv_silu2_k(const float* __restrict__ proj, const float* __restrict__ cw,
                  const float* __restrict__ cb,
                  unsigned short* __restrict__ XT, unsigned short* __restrict__ Bg,
                  unsigned short* __restrict__ Btg, unsigned short* __restrict__ Cg)
{
    __shared__ __attribute__((aligned(16))) unsigned short T[64][264];
    const int bd = blockIdx.x % 68, bt = blockIdx.x / 68;
    const int d0 = bd * 64, t0 = bt * 256;
    const int tid = threadIdx.x;
    const int dl = tid & 63;
    const int d = d0 + dl;
    const float b0 = cb[d];
    const float w0 = cw[d * 4 + 0], w1 = cw[d * 4 + 1];
    const float w2 = cw[d * 4 + 2], w3 = cw[d * 4 + 3];
    for (int it = 0; it < 64; ++it) {
        int tl = it * 4 + (tid >> 6);
        int t = t0 + tl;
        const float* pc = &proj[(size_t)t * kProj + kI + d];
        float acc = b0 + w3 * pc[0];
        if (t >= 1) acc += w2 * pc[-(ptrdiff_t)kProj];
        if (t >= 2) acc += w1 * pc[-(ptrdiff_t)(2 * kProj)];
        if (t >= 3) acc += w0 * pc[-(ptrdiff_t)(3 * kProj)];
        T[dl][tl] = f2bf(siluf(acc));
    }
    __syncthreads();

    if (d0 < kI) {                       // X: XT[d][t], rows along t (coalesced)
        int row = tid >> 2, cg = (tid & 3) * 64;
#pragma unroll
        for (int j = 0; j < 8; ++j)
            *(ushort8v*)&XT[(size_t)(d0 + row) * kS + t0 + cg + j * 8] =
                *(const ushort8v*)&T[row][cg + j * 8];
    } else if (d0 < kI + kN) {           // B: Bt[n][t] + Bg[t][n]
        int n0 = d0 - kI;
        int row = tid >> 2, cg = (tid & 3) * 64;
#pragma unroll
        for (int j = 0; j < 8; ++j)
            *(ushort8v*)&Btg[(size_t)(n0 + row) * kS + t0 + cg + j * 8] =
                *(const ushort8v*)&T[row][cg + j * 8];
        for (int pass = 0; pass < 16; ++pass) {
            int tl = pass * 16 + (tid >> 4), nq = (tid & 15) * 4;
            ushort4 v = {T[nq][tl], T[nq + 1][tl], T[nq + 2][tl], T[nq + 3][tl]};
            *(ushort4*)&Bg[(size_t)(t0 + tl) * kN + n0 + nq] = v;
        }
    } else {                             // C: Cg[t][n]
        int n0 = d0 - (kI + kN);
        for (int pass = 0; pass < 16; ++pass) {
            int tl = pass * 16 + (tid >> 4), nq = (tid & 15) * 4;
            ushort4 v = {T[nq][tl], T[nq + 1][tl], T[nq + 2][tl], T[nq + 3][tl]};
            *(ushort4*)&Cg[(size_t)(t0 + tl) * kN + n0 + nq] = v;
        }
    }
}

// ---------- dt = softplus(proj_dt + bias); per-chunk cumsum(dt*A) ----------
__global__ __launch_bounds__(256)
void dt_cumsum_k(const float* __restrict__ proj, const float* __restrict__ dt_bias,
                 const float* __restrict__ A_log, float* __restrict__ dt,
                 float* __restrict__ acum)
{
    __shared__ float wsum[4];
    const int c = blockIdx.x >> 6, h = blockIdx.x & 63;
    const int l = threadIdx.x, t = c * kChunk + l;
    float a = -expf(A_log[h]);
    float z = proj[(size_t)t * kProj + kI + kConv + h] + dt_bias[h];
    float d = (z > 20.f) ? z : log1pf(expf(z));
    dt[t * kH + h] = d;
    float v = d * a;
    int lane = l & 63, w = l >> 6;
#pragma unroll
    for (int off = 1; off < 64; off <<= 1) {
        float u = __shfl_up(v, off);
        if (lane >= off) v += u;
    }
    if (lane == 63) wsum[w] = v;
    __syncthreads();
    float add = 0.f;
    for (int i = 0; i < w; ++i) add += wsum[i];
    acum[t * kH + h] = v + add;
}

// ---------- states (v2): bf16 MFMA. out[p][n] = sum_s Xw^T[p][s] Bt[n][s] ---
__global__ __launch_bounds__(256)
void states2_k(const unsigned short* __restrict__ XT,
               const unsigned short* __restrict__ Btg,
               const float* __restrict__ dt, const float* __restrict__ acum,
               float* __restrict__ states)
{
    __shared__ __attribute__((aligned(16))) unsigned short Aw[64 * 72];
    __shared__ __attribute__((aligned(16))) unsigned short Bs[128 * 64];
    __shared__ float Wl[256];
    const int c = blockIdx.x >> 6, h = blockIdx.x & 63;
    const int tid = threadIdx.x;
    const int wave = tid >> 6, lane = tid & 63;
    const int quad = lane >> 4, l15 = lane & 15;
    const float aend = acum[(size_t)(c * kChunk + 255) * kH + h];
    {
        int t = c * kChunk + tid;
        Wl[tid] = __expf(aend - acum[(size_t)t * kH + h]) * dt[(size_t)t * kH + h];
    }
    __syncthreads();

    floatx4 acc[4][2] = {};
    for (int lt = 0; lt < 4; ++lt) {
        const int s0 = c * kChunk + lt * 64;
#pragma unroll
        for (int i = 0; i < 2; ++i) {       // Aw[p][s] = XT * w, stride 72
            int f = tid + 256 * i;
            int p = f >> 3, sc = (f & 7) * 8;
            ushort8v xv = *(const ushort8v*)&XT[(size_t)(h * 64 + p) * kS + s0 + sc];
            ushort8v o;
#pragma unroll
            for (int j = 0; j < 8; ++j)
                o[j] = f2bf(bf2f(xv[j]) * Wl[lt * 64 + sc + j]);
            *(ushort8v*)&Aw[p * 72 + sc] = o;
        }
#pragma unroll
        for (int i = 0; i < 4; ++i) {       // Bs[n][s], phys chunk = lg ^ (n&7)
            int f = tid + 256 * i;
            int n = f >> 3, ph = f & 7, lg = ph ^ (n & 7);
            gll16(&Btg[(size_t)n * kS + s0 + lg * 8], &Bs[(size_t)f * 8]);
        }
        __syncthreads();
#pragma unroll
        for (int ks = 0; ks < 2; ++ks) {
            short8 bfr[2];
#pragma unroll
            for (int nj = 0; nj < 2; ++nj) {
                int n = (wave * 2 + nj) * 16 + l15;
                int ph = (ks * 4 + quad) ^ (n & 7);
                bfr[nj] = *(const short8*)&Bs[n * 64 + ph * 8];
            }
#pragma unroll
            for (int pi = 0; pi < 4; ++pi) {
                short8 af = *(const short8*)&Aw[(pi * 16 + l15) * 72 + ks * 32 + quad * 8];
                acc[pi][0] = __builtin_amdgcn_mfma_f32_16x16x32_bf16(af, bfr[0], acc[pi][0], 0, 0, 0);
                acc[pi][1] = __builtin_amdgcn_mfma_f32_16x16x32_bf16(af, bfr[1], acc[pi][1], 0, 0, 0);
            }
        }
        __syncthreads();
    }
    const size_t base = (size_t)(c * kH + h) * (kP * kN);
#pragma unroll
    for (int pi = 0; pi < 4; ++pi)
#pragma unroll
        for (int nj = 0; nj < 2; ++nj) {
            int n = (wave * 2 + nj) * 16 + l15;
#pragma unroll
            for (int r = 0; r < 4; ++r)
                states[base + (size_t)(pi * 16 + quad * 4 + r) * kN + n] = acc[pi][nj][r];
        }
}

// ---------- sequential inter-chunk recurrence ----------
__global__ __launch_bounds__(256)
void scan_k(const float* __restrict__ states, const float* __restrict__ acum,
            float* __restrict__ prev)
{
    const int h = blockIdx.x >> 3, seg = blockIdx.x & 7;
    const int e = (seg * 256 + threadIdx.x) * 4;
    float4 carry = make_float4(0.f, 0.f, 0.f, 0.f);
    for (int c = 0; c < kNC; ++c) {
        size_t base = (size_t)(c * kH + h) * (kP * kN);
        *(float4*)&prev[base + e] = carry;
        float dec = __expf(acum[(size_t)(c * kChunk + 255) * kH + h]);
        float4 st = *(const float4*)&states[base + e];
        carry.x = carry.x * dec + st.x; carry.y = carry.y * dec + st.y;
        carry.z = carry.z * dec + st.z; carry.w = carry.w * dec + st.w;
    }
}

// ---------- SSD Y (v4): gll16-staged bf16 tiles, XOR-swizzled ----------
__global__ __launch_bounds__(256)
void ssd_y4_k(const unsigned short* __restrict__ Cg,
              const unsigned short* __restrict__ Bg,
              const unsigned short* __restrict__ XT,
              const float* __restrict__ dt, const float* __restrict__ acum,
              const float* __restrict__ prev, const float* __restrict__ Dp,
              float* __restrict__ Y)
{
    __shared__ __attribute__((aligned(16))) unsigned short Cb[64 * 128];
    __shared__ __attribute__((aligned(16))) unsigned short Bb[64 * 128];
    __shared__ __attribute__((aligned(16))) unsigned short Xt[64 * 64];
    __shared__ __attribute__((aligned(16))) unsigned short Wb[64 * 72];
    __shared__ float At[64], Asv[64], Dtv[64];

    const int bi = blockIdx.x;
    const int ti = bi & 3, h = (bi >> 2) & 63, c = bi >> 8;
    const int tid = threadIdx.x;
    const int wave = tid >> 6, lane = tid & 63;
    const int quad = lane >> 4, l15 = lane & 15;
    const int trow0 = c * kChunk + ti * 64;
    const float Dh = Dp[h];

#pragma unroll
    for (int i = 0; i < 4; ++i) {
        int f = tid + 256 * i;
        int row = f >> 4, ph = f & 15, lg = ph ^ (row & 15);
        gll16(&Cg[(size_t)(trow0 + row) * kN + lg * 8], &Cb[(size_t)f * 8]);
    }
    const size_t pbase = (size_t)(c * kH + h) * (kP * kN);
#pragma unroll
    for (int r = 0; r < 8; ++r) {
        int f = tid + 256 * r;
        int row = f >> 5, c4 = (f & 31) * 4;          // 4 fp32 = half a 16B chunk
        float4 v = *(const float4*)&prev[pbase + (size_t)row * kN + c4];
        ushort4 u = {f2bf(v.x), f2bf(v.y), f2bf(v.z), f2bf(v.w)};
        int dst = row * 128 + ((((f & 31) >> 1) ^ (row & 15)) * 8) + (f & 1) * 4;
        *(ushort4*)&Bb[dst] = u;
    }
    if (tid < 64) At[tid] = acum[(size_t)(trow0 + tid) * kH + h];
    __syncthreads();

    floatx4 yacc[4] = {};
#pragma unroll
    for (int ks = 0; ks < 4; ++ks) {
        int cha = (ks * 4 + quad) ^ l15;
        short8 a = *(const short8*)&Cb[(wave * 16 + l15) * 128 + cha * 8];
#pragma unroll
        for (int ni = 0; ni < 4; ++ni) {
            short8 b = *(const short8*)&Bb[(ni * 16 + l15) * 128 + cha * 8];
            yacc[ni] = __builtin_amdgcn_mfma_f32_16x16x32_bf16(a, b, yacc[ni], 0, 0, 0);
        }
    }
    {
        float eAr[4];
#pragma unroll
        for (int r = 0; r < 4; ++r) eAr[r] = __expf(At[wave * 16 + quad * 4 + r]);
#pragma unroll
        for (int ni = 0; ni < 4; ++ni)
#pragma unroll
            for (int r = 0; r < 4; ++r) yacc[ni][r] *= eAr[r];
    }

    for (int si = 0; si <= ti; ++si) {
        const int srow0 = c * kChunk + si * 64;
        __syncthreads();
#pragma unroll
        for (int i = 0; i < 4; ++i) {       // B tile
            int f = tid + 256 * i;
            int row = f >> 4, ph = f & 15, lg = ph ^ (row & 15);
            gll16(&Bg[(size_t)(srow0 + row) * kN + lg * 8], &Bb[(size_t)f * 8]);
        }
#pragma unroll
        for (int i = 0; i < 2; ++i) {       // X^T tile [p][s]
            int f = tid + 256 * i;
            int p = f >> 3, ph = f & 7, lg = ph ^ (p & 7);
            gll16(&XT[(size_t)(h * 64 + p) * kS + srow0 + lg * 8], &Xt[(size_t)f * 8]);
        }
        if (tid < 64) {
            Asv[tid] = acum[(size_t)(srow0 + tid) * kH + h];
            Dtv[tid] = dt[(size_t)(srow0 + tid) * kH + h];
        }
        __syncthreads();

        floatx4 sacc[4] = {};
#pragma unroll
        for (int ks = 0; ks < 4; ++ks) {
            int cha = (ks * 4 + quad) ^ l15;
            short8 a = *(const short8*)&Cb[(wave * 16 + l15) * 128 + cha * 8];
#pragma unroll
            for (int ni = 0; ni < 4; ++ni) {
                short8 b = *(const short8*)&Bb[(ni * 16 + l15) * 128 + cha * 8];
                sacc[ni] = __builtin_amdgcn_mfma_f32_16x16x32_bf16(a, b, sacc[ni], 0, 0, 0);
            }
        }

        const bool diag = (si == ti);
#pragma unroll
        for (int ni = 0; ni < 4; ++ni) {
            int s_ = ni * 16 + l15;
            float as = Asv[s_], dts = Dtv[s_];
#pragma unroll
            for (int r = 0; r < 4; ++r) {
                int tl = wave * 16 + quad * 4 + r;
                float w = sacc[ni][r] * __expf(At[tl] - as) * dts;
                if (diag) {
                    if (s_ > tl) w = 0.f;
                    else if (s_ == tl) w += Dh;
                }
                Wb[tl * 72 + s_] = f2bf(w);
            }
        }
#pragma unroll
        for (int ks = 0; ks < 2; ++ks) {
            short8 aw = *(const short8*)&Wb[(wave * 16 + l15) * 72 + ks * 32 + quad * 8];
#pragma unroll
            for (int ni = 0; ni < 4; ++ni) {
                int ph = ((ks * 4 + quad) ^ (l15 & 7)) * 8;
                short8 xb = *(const short8*)&Xt[(ni * 16 + l15) * 64 + ph];
                yacc[ni] = __builtin_amdgcn_mfma_f32_16x16x32_bf16(aw, xb, yacc[ni], 0, 0, 0);
            }
        }
    }

#pragma unroll
    for (int ni = 0; ni < 4; ++ni)
#pragma unroll
        for (int r = 0; r < 4; ++r)
            Y[(size_t)(trow0 + wave * 16 + quad * 4 + r) * kI + h * kP + ni * 16 + l15]
                = yacc[ni][r];
}

// ---------- gated RMSNorm -> bf16 ----------
__global__ __launch_bounds__(256)
void rmsnorm_gate_k(const float* __restrict__ Y, const float* __restrict__ proj,
                    const float* __restrict__ nw, unsigned short* __restrict__ Yb)
{
    __shared__ float red[4];
    const int t = blockIdx.x, tid = threadIdx.x;
    const float* yrow = &Y[(size_t)t * kI];
    const float* grow = &proj[(size_t)t * kProj];
    float v[16];
    float ss = 0.f;
#pragma unroll
    for (int j = 0; j < 4; ++j) {
        int i = (tid + 256 * j) * 4;
        float4 y4 = *(const float4*)&yrow[i];
        float4 g4 = *(const float4*)&grow[i];
        float a = y4.x * siluf(g4.x), bq = y4.y * siluf(g4.y);
        float cq = y4.z * siluf(g4.z), d = y4.w * siluf(g4.w);
        v[j * 4 + 0] = a; v[j * 4 + 1] = bq; v[j * 4 + 2] = cq; v[j * 4 + 3] = d;
        ss += a * a + bq * bq + cq * cq + d * d;
    }
#pragma unroll
    for (int off = 32; off > 0; off >>= 1) ss += __shfl_down(ss, off);
    if ((tid & 63) == 0) red[tid >> 6] = ss;
    __syncthreads();
    float sum = red[0] + red[1] + red[2] + red[3];
    float rr = rsqrtf(sum * (1.f / kI) + kEps);
#pragma unroll
    for (int j = 0; j < 4; ++j) {
        int i = (tid + 256 * j) * 4;
        float4 w4 = *(const float4*)&nw[i];
        ushort4 o;
        o.x = f2bf(v[j * 4 + 0] * rr * w4.x);
        o.y = f2bf(v[j * 4 + 1] * rr * w4.y);
        o.z = f2bf(v[j * 4 + 2] * rr * w4.z);
        o.w = f2bf(v[j * 4 + 3] * rr * w4.w);
        *(ushort4*)&Yb[(size_t)t * kI + i] = o;
    }
}

extern "C" void kernel_launch(void* const* d_in, const int* in_sizes, int n_in,
                              void* d_out, int out_size, void* d_ws, size_t ws_size,
                              hipStream_t stream)
{
    const float* x       = (const float*)d_in[0];
    const float* W_in    = (const float*)d_in[1];
    const float* conv_w  = (const float*)d_in[2];
    const float* conv_b  = (const float*)d_in[3];
    const float* dt_bias = (const float*)d_in[4];
    const float* A_log   = (const float*)d_in[5];
    const float* Dp      = (const float*)d_in[6];
    const float* norm_w  = (const float*)d_in[7];
    const float* W_out   = (const float*)d_in[8];
    float* out = (float*)d_out;

    float* ws   = (float*)d_ws;
    float* proj = ws;                                       // 2048*8512 f
    unsigned short* XT  = (unsigned short*)(proj + (size_t)kS * kProj);  // 4096*2048
    unsigned short* Bg  = XT + (size_t)kI * kS;             // 2048*128
    unsigned short* Btg = Bg + (size_t)kS * kN;             // 128*2048
    unsigned short* Cg  = Btg + (size_t)kN * kS;            // 2048*128
    float* dtb  = (float*)(Cg + (size_t)kS * kN);           // 2048*64
    float* acum = dtb + (size_t)kS * kH;                    // 2048*64
    float* prev = acum + (size_t)kS * kH;                   // 4,194,304 f
    float* Y    = prev + (size_t)kNC * kH * kP * kN;        // 8,388,608 f
    float* states = Y;
    unsigned short* xb  = XT;                               // early alias
    unsigned short* Wb  = (unsigned short*)prev;            // early (spans into Y)
    unsigned short* Yb  = (unsigned short*)prev;            // late
    unsigned short* Wob = XT;                               // late
    // strip partials: after Wb's float-equivalent footprint; inside prev+Y.
    float* Pstrip = prev + ((size_t)kProj * kHID) / 2;
    // out-GEMM partials: proj region (dead after rmsnorm reads the gate).
    float* Pout = proj;

    dim3 blk(256);
    const int kNmain = 8192;               // 32 x 256-col tiles -> 256 blocks
    cast_bf16_k<<<(kS * kHID) / 2048, blk, 0, stream>>>(x, xb);
    cast_bf16_k<<<(kProj * kHID) / 2048, blk, 0, stream>>>(W_in, Wb);
    gemm_bt_8ph<<<(kS >> 8) * (kNmain >> 8), dim3(512), 0, stream>>>(
        xb, Wb, proj, kS, kNmain, kHID, kHID, kProj);
    gemm_strip_sk<<<192, blk, 0, stream>>>(
        xb, Wb + (size_t)kNmain * kHID, Pstrip, kHID);
    strip_reduce_k<<<(kS * 320) / 1024, blk, 0, stream>>>(Pstrip, proj);
    conv_silu2_k<<<68 * 8, blk, 0, stream>>>(proj, conv_w, conv_b, XT, Bg, Btg, Cg);
    dt_cumsum_k<<<kNC * kH, blk, 0, stream>>>(proj, dt_bias, A_log, dtb, acum);
    states2_k<<<kNC * kH, blk, 0, stream>>>(XT, Btg, dtb, acum, states);
    scan_k<<<kH * 8, blk, 0, stream>>>(states, acum, prev);
    ssd_y4_k<<<kNC * kH * 4, blk, 0, stream>>>(Cg, Bg, XT, dtb, acum, prev, Dp, Y);
    rmsnorm_gate_k<<<kS, blk, 0, stream>>>(Y, proj, norm_w, Yb);
    cast_bf16_k<<<(kHID * kI) / 2048, blk, 0, stream>>>(W_out, Wob);
    // out GEMM: 2-phase 256^2, split-K=4 (grid 4*64), K=1024 per block.
    gemm_bt_8ph<<<4 * (kS >> 8) * (kHID >> 8), dim3(512), 0, stream>>>(
        Yb, Wob, Pout, kS, kHID, kHID / 2, kI, kHID);
    out_reduce4_k<<<(kS * kHID) / 1024, blk, 0, stream>>>(Pout, out);
}